// Round 2
// 687.118 us; speedup vs baseline: 1.2140x; 1.2140x over previous
//
#include <hip/hip_runtime.h>
#include <hip/hip_bf16.h>

typedef unsigned short u16;
typedef __attribute__((ext_vector_type(8))) short bf16x8;
typedef __attribute__((ext_vector_type(4))) float f32x4;

#define Bc 4
#define Sc 8192
#define Fc 512
#define Nc 64
#define Hc 2048
#define Tc 32768
#define SIXF 3072

__device__ __forceinline__ u16 f2bf(float v) {
  __hip_bfloat16 h = __float2bfloat16(v);
  return *reinterpret_cast<u16*>(&h);
}
__device__ __forceinline__ float bf2f(u16 u) {
  return __uint_as_float(((unsigned)u) << 16);
}
__device__ __forceinline__ float ldf(const void* p, long i, int bf) {
  return bf ? bf2f(((const u16*)p)[i]) : ((const float*)p)[i];
}

// async global->LDS, 16 bytes per lane. LDS dest is wave-uniform base + lane*16.
__device__ __forceinline__ void ld16(const u16* g, u16* l) {
  __builtin_amdgcn_global_load_lds(
      (const __attribute__((address_space(1))) unsigned int*)g,
      (__attribute__((address_space(3))) unsigned int*)l,
      16, 0, 0);
}

// XCD-aware bijective block remap (valid when nwg % 8 == 0; identity otherwise).
__device__ __forceinline__ void xcd_swz(int& bx, int& by) {
  int gx = gridDim.x;
  int nwg = gx * gridDim.y;
  int lin = blockIdx.x + gx * blockIdx.y;
  if ((nwg & 7) == 0) {
    int q = nwg >> 3;
    lin = (lin & 7) * q + (lin >> 3);
  }
  bx = lin % gx;
  by = lin / gx;
}

// ---------- dtype detection ----------
__global__ void k_detect(const u16* __restrict__ x, int* __restrict__ flag) {
  if (threadIdx.x == 0) {
    int cnt = 0;
    for (int i = 0; i < 256; ++i) {
      int e = (x[i] >> 7) & 0xFF;
      cnt += (e >= 130);
    }
    *flag = (cnt >= 16) ? 0 : 1;   // 1 = bf16 inputs, 0 = fp32
  }
}

__global__ void k_convert(const void* __restrict__ src, float* __restrict__ dst,
                          int n, const int* __restrict__ flag) {
  int bf = *flag;
  int i = blockIdx.x * blockDim.x + threadIdx.x;
  int stride = gridDim.x * blockDim.x;
  for (int j = i; j < n; j += stride) dst[j] = ldf(src, j, bf);
}

// ---------- mods: init with ada_b, then f-chunked atomic accumulation ----------
__global__ __launch_bounds__(256) void k_mods_init(const void* __restrict__ ada_b,
                                                   const int* __restrict__ flag,
                                                   float* __restrict__ mods) {
  int bf = *flag;
  int col = blockIdx.x * 256 + threadIdx.x;   // grid 12
  float v = ldf(ada_b, col, bf);
  for (int b = 0; b < Bc; ++b) mods[b * SIXF + col] = v;
}

__global__ __launch_bounds__(256) void k_mods2(const void* __restrict__ cond,
                                               const void* __restrict__ ada_w,
                                               const int* __restrict__ flag,
                                               float* __restrict__ mods) {
  int bf = *flag;
  int b = blockIdx.y;
  int f0 = blockIdx.z * 128;
  int col = blockIdx.x * 256 + threadIdx.x;
  __shared__ float sc[128];
  for (int i = threadIdx.x; i < 128; i += 256) {
    float c = ldf(cond, b * Fc + f0 + i, bf);
    sc[i] = c / (1.f + expf(-c));
  }
  __syncthreads();
  float acc = 0.f;
  for (int f = 0; f < 128; ++f) acc = fmaf(sc[f], ldf(ada_w, (long)(f0 + f) * SIXF + col, bf), acc);
  atomicAdd(&mods[b * SIXF + col], acc);
}

// ---------- Abar + Wbu packed, f-chunked ----------
__global__ void k_prep(const void* lAf, const void* Aif, const void* Brf, const void* Bif, const void* ldtf,
                       const void* lAb, const void* Aib, const void* Brb, const void* Bib, const void* ldtb,
                       const int* __restrict__ flag,
                       u16* __restrict__ Wbup, float* __restrict__ Abar) {
  int bf = *flag;
  int dir = blockIdx.x;
  int f0 = blockIdx.y * 64;     // grid (2, 8)
  int n = threadIdx.x;          // 64
  const void* lA = dir ? lAb : lAf;
  const void* Ai = dir ? Aib : Aif;
  const void* Br = dir ? Brb : Brf;
  const void* Bi = dir ? Bib : Bif;
  const void* ld = dir ? ldtb : ldtf;
  float dt  = expf(ldf(ld, n, bf));
  float Are = -expf(ldf(lA, n, bf));
  float Aim = ldf(Ai, n, bf);
  float er  = expf(Are * dt);
  float abr = er * cosf(Aim * dt);
  float abi = er * sinf(Aim * dt);
  if (blockIdx.y == 0) {
    Abar[(dir * Nc + n) * 2 + 0] = abr;
    Abar[(dir * Nc + n) * 2 + 1] = abi;
  }
  float dr = Are + 1e-8f, di = Aim;
  float den = dr * dr + di * di;
  float nr = abr - 1.f, ni = abi;
  float cr = (nr * dr + ni * di) / den;
  float ci = (ni * dr - nr * di) / den;
  int col_re = dir * 128 + n, col_im = dir * 128 + 64 + n;
  for (int f = f0; f < f0 + 64; ++f) {
    float br = ldf(Br, n * Fc + f, bf), bi = ldf(Bi, n * Fc + f, bf);
    Wbup[(((f >> 3) * 256) + col_re) * 8 + (f & 7)] = f2bf(cr * br - ci * bi);
    Wbup[(((f >> 3) * 256) + col_im) * 8 + (f & 7)] = f2bf(cr * bi + ci * br);
  }
}

// P2 packed bf16 [512/8][512][8]
__global__ __launch_bounds__(256) void k_P2p(const void* Df, const void* Db, const void* pw,
                                             const int* __restrict__ flag, u16* __restrict__ P2p) {
  int bf = *flag;
  int idx = blockIdx.x * 256 + threadIdx.x;
  int f1 = idx >> 9, fo = idx & 511;
  float v = ldf(Df, f1, bf) * ldf(pw, (long)f1 * Fc + fo, bf) +
            ldf(Db, f1, bf) * ldf(pw, (long)(Fc + f1) * Fc + fo, bf);
  P2p[(((f1 >> 3) * Fc) + fo) * 8 + (f1 & 7)] = f2bf(v);
}

// Cpm bf16 [256][512]: row k=dir*128+c*64+n, Cpm[k][f] = (+Cre|-Cim)[f][n]
__global__ __launch_bounds__(256) void k_Cpm(const void* Cref, const void* Cimf,
                                             const void* Creb, const void* Cimb,
                                             const int* __restrict__ flag, u16* __restrict__ Cpm) {
  int bf = *flag;
  int k = blockIdx.x;
  int dir = k >> 7, c = (k >> 6) & 1, n = k & 63;
  const void* C = dir ? (c ? Cimb : Creb) : (c ? Cimf : Cref);
  float sgn = c ? -1.f : 1.f;
  for (int f = threadIdx.x; f < Fc; f += 256)
    Cpm[k * Fc + f] = f2bf(sgn * ldf(C, (long)f * Nc + n, bf));
}

// generic raw [K,N] -> packed bf16 [K/8][N][8]; one thread per (k8,n)
__global__ __launch_bounds__(256) void k_Wpack(const void* __restrict__ src, const int* __restrict__ flag,
                                               int log2N, u16* __restrict__ dst) {
  int bf = *flag;
  long i = (long)blockIdx.x * 256 + threadIdx.x;     // over (K/8)*N
  int Nn = 1 << log2N;
  long k8 = i >> log2N;
  int n = (int)(i & (Nn - 1));
  u16 tmp[8];
#pragma unroll
  for (int j = 0; j < 8; ++j)
    tmp[j] = f2bf(ldf(src, ((k8 << 3) + j) * (long)Nn + n, bf));
  *(ushort4*)(dst + i * 8)     = *(ushort4*)tmp;
  *(ushort4*)(dst + i * 8 + 4) = *(ushort4*)(tmp + 4);
}

// ---------- LayerNorm + AdaLN ----------
__global__ __launch_bounds__(256) void k_ln(const void* __restrict__ src, int srcmode,
                                            long src_tok_base, int b0,
                                            const int* __restrict__ flag,
                                            const float* __restrict__ mods,
                                            int sh_base, int sc_base,
                                            u16* __restrict__ dst) {
  int bf = srcmode ? 1 : *flag;
  long lt = blockIdx.x;
  int b = b0 + (int)(lt >> 13);
  int t = threadIdx.x;
  long si = (src_tok_base + lt) * Fc;
  float x0 = ldf(src, si + t, bf);
  float x1 = ldf(src, si + t + 256, bf);
  float s = x0 + x1, qq = x0 * x0 + x1 * x1;
  for (int o = 32; o; o >>= 1) { s += __shfl_down(s, o); qq += __shfl_down(qq, o); }
  __shared__ float ss[4], sq[4];
  int w = t >> 6;
  if ((t & 63) == 0) { ss[w] = s; sq[w] = qq; }
  __syncthreads();
  float S = ss[0] + ss[1] + ss[2] + ss[3];
  float Q = sq[0] + sq[1] + sq[2] + sq[3];
  float mu = S * (1.f / Fc);
  float var = Q * (1.f / Fc) - mu * mu;
  float rs = rsqrtf(var + 1e-5f);
  const float* mb = mods + b * SIXF;
  float h0 = (x0 - mu) * rs * (1.f + mb[sc_base + t]) + mb[sh_base + t];
  float h1 = (x1 - mu) * rs * (1.f + mb[sc_base + t + 256]) + mb[sh_base + t + 256];
  dst[lt * Fc + t] = f2bf(h0);
  dst[lt * Fc + t + 256] = f2bf(h1);
}

// ---------- MFMA GEMM core ----------
// A staged via global_load_lds with PRE-SWIZZLED global source (linear LDS dest,
// XOR-swizzled read): LDS chunk c holds A[m][kc] with m=c>>3, kc=(c&7)^(m&7).
// W staged linearly. 16B per lane per issue.
struct Smem { u16 As[128 * 64]; u16 Ws[64 * 128]; };

__device__ __forceinline__ void mfma_gemm(Smem& sm, const u16* __restrict__ A, long row0, int K,
                                          const u16* __restrict__ Wp, int N, int col0,
                                          f32x4 (&acc)[4][4]) {
  const int tid = threadIdx.x;
  const int l = tid & 63;
  const int q = l >> 4, li = l & 15;
  const int w = tid >> 6;
  const int wm = (w >> 1) << 6, wn = (w & 1) << 6;
  // per-thread loop-invariant source offsets (elements)
  const int m0 = tid >> 3;
  const int kc0 = (tid & 7) ^ (m0 & 7);            // invariant under c += 256 (m += 32)
  const long aoff0 = (row0 + m0) * (long)K + (kc0 << 3);
  const long woff0 = (long)(tid >> 7) * ((long)N << 3) + ((long)(col0 + (tid & 127)) << 3);
  u16* asdst = sm.As + ((w << 6) << 3);            // wave-uniform LDS base
  u16* wsdst = sm.Ws + ((w << 6) << 3);
  for (int k0 = 0; k0 < K; k0 += 64) {
    __syncthreads();
#pragma unroll
    for (int it = 0; it < 4; ++it)
      ld16(A + aoff0 + (long)it * ((long)K << 5) + k0, asdst + (it << 11));
#pragma unroll
    for (int it = 0; it < 4; ++it)
      ld16(Wp + woff0 + (long)k0 * N + (long)it * ((long)N << 4), wsdst + (it << 11));
    __syncthreads();
#pragma unroll
    for (int ks = 0; ks < 2; ++ks) {
      bf16x8 af[4], bw[4];
#pragma unroll
      for (int mt = 0; mt < 4; ++mt) {
        int mrow = wm + (mt << 4) + li;
        af[mt] = *(const bf16x8*)(sm.As + (((mrow << 3) + (((ks << 2) + q) ^ (mrow & 7))) << 3));
      }
#pragma unroll
      for (int nt = 0; nt < 4; ++nt) {
        int n = wn + (nt << 4) + li;
        bw[nt] = *(const bf16x8*)(sm.Ws + ((((((ks << 2) + q) << 7) + n)) << 3));
      }
#pragma unroll
      for (int mt = 0; mt < 4; ++mt)
#pragma unroll
        for (int nt = 0; nt < 4; ++nt)
          acc[mt][nt] = __builtin_amdgcn_mfma_f32_16x16x32_bf16(af[mt], bw[nt], acc[mt][nt], 0, 0, 0);
    }
  }
}

// G via MFMA: Cpm[256,512] @ pwp(dir half) -> packed Gp
__global__ __launch_bounds__(256) void k_Gp2(const u16* __restrict__ Cpm, const u16* __restrict__ pwp,
                                             u16* __restrict__ Gp) {
  __shared__ Smem sm;
  f32x4 acc[4][4] = {};
  int bx, by; xcd_swz(bx, by);
  long row0 = (long)by * 128;
  int col0 = bx << 7;
  int dir = (int)(row0 >> 7);
  mfma_gemm(sm, Cpm, row0, Fc, pwp + (size_t)dir * 262144, Fc, col0, acc);
  const int l = threadIdx.x & 63, q = l >> 4, li = l & 15;
  const int w = threadIdx.x >> 6;
  const int wm = (w >> 1) << 6, wn = (w & 1) << 6;
#pragma unroll
  for (int mt = 0; mt < 4; ++mt)
#pragma unroll
    for (int nt = 0; nt < 4; ++nt)
#pragma unroll
      for (int r = 0; r < 4; ++r) {
        int k = (int)row0 + wm + (mt << 4) + (q << 2) + r;
        int col = col0 + wn + (nt << 4) + li;
        Gp[(((k >> 3) * Fc) + col) * 8 + (k & 7)] = f2bf(acc[mt][nt][r]);
      }
}

// Bu GEMM: h[nb*8192,512] @ Wbu -> Bu[dir][lb][n][s][2] (bwd s flipped)
__global__ __launch_bounds__(256) void k_gemm_bu(const u16* __restrict__ h,
                                                 const u16* __restrict__ Wbup,
                                                 int nb, float* __restrict__ Bu) {
  __shared__ Smem sm;
  f32x4 acc[4][4] = {};
  int bx, by; xcd_swz(bx, by);
  long row0 = (long)by * 128;
  int col0 = bx << 7;
  mfma_gemm(sm, h, row0, Fc, Wbup, 256, col0, acc);
  const int l = threadIdx.x & 63, q = l >> 4, li = l & 15;
  const int w = threadIdx.x >> 6;
  const int wm = (w >> 1) << 6, wn = (w & 1) << 6;
#pragma unroll
  for (int mt = 0; mt < 4; ++mt) {
#pragma unroll
    for (int nt = 0; nt < 4; ++nt) {
      int col = col0 + wn + (nt << 4) + li;
      int dir = col >> 7, cc = (col >> 6) & 1, n = col & 63;
#pragma unroll
      for (int r = 0; r < 4; ++r) {
        long lt = row0 + wm + (mt << 4) + (q << 2) + r;
        int lb = (int)(lt >> 13), s = (int)(lt & 8191);
        int spos = dir ? (Sc - 1 - s) : s;
        Bu[((((long)dir * nb + lb) * Nc + n) * Sc + spos) * 2 + cc] = acc[mt][nt][r];
      }
    }
  }
}

// chunked complex linear scan, in-place on Bu (float4 I/O). One block per (dir,lb,n).
__global__ __launch_bounds__(256) void k_scan(float* __restrict__ Bu, const float* __restrict__ Abar,
                                              int nb) {
  int blk = blockIdx.x;
  int per_dir = nb * 64;
  int dir = blk / per_dir;
  int rem = blk - dir * per_dir;
  int lb = rem >> 6, n = rem & 63;
  float ar = Abar[(dir * Nc + n) * 2 + 0];
  float ai = Abar[(dir * Nc + n) * 2 + 1];
  float* base = Bu + (((long)dir * nb + lb) * Nc + n) * Sc * 2;
  int t = threadIdx.x;
  float4 loc[16];
  float lr = 0.f, li = 0.f;
  const float4* bp = (const float4*)base + t * 16;
#pragma unroll
  for (int j = 0; j < 16; ++j) {
    float4 v = bp[j];
    loc[j] = v;
    float nr = fmaf(ar, lr, fmaf(-ai, li, v.x));
    float ni = fmaf(ar, li, fmaf(ai, lr, v.y));
    lr = fmaf(ar, nr, fmaf(-ai, ni, v.z));
    li = fmaf(ar, ni, fmaf(ai, nr, v.w));
  }
  __shared__ float sr[256], si[256];
  float pr = ar, pi = ai;
  for (int k = 0; k < 5; ++k) { float t2 = pr * pr - pi * pi; pi = 2.f * pr * pi; pr = t2; }  // a^32
  float vr = lr, vi = li;
  for (int step = 1; step < 256; step <<= 1) {
    sr[t] = vr; si[t] = vi;
    __syncthreads();
    if (t >= step) {
      float orr = sr[t - step], oii = si[t - step];
      vr = vr + pr * orr - pi * oii;
      vi = vi + pr * oii + pi * orr;
    }
    __syncthreads();
    float t2 = pr * pr - pi * pi; pi = 2.f * pr * pi; pr = t2;
  }
  sr[t] = vr; si[t] = vi;
  __syncthreads();
  float xr = (t == 0) ? 0.f : sr[t - 1];
  float xi = (t == 0) ? 0.f : si[t - 1];
  float4* op = (float4*)base + t * 16;
#pragma unroll
  for (int j = 0; j < 16; ++j) {
    float4 v = loc[j];
    float nr = fmaf(ar, xr, fmaf(-ai, xi, v.x));
    float ni = fmaf(ar, xi, fmaf(ai, xr, v.y));
    xr = fmaf(ar, nr, fmaf(-ai, ni, v.z));
    xi = fmaf(ar, ni, fmaf(ai, nr, v.w));
    float4 o; o.x = nr; o.y = ni; o.z = xr; o.w = xi;
    op[j] = o;
  }
}

// gather xs -> token-major bf16 hi/lo via LDS transpose (32 tokens x 256 cols per block)
__global__ __launch_bounds__(256) void k_xs_t(const float* __restrict__ xs, int nb,
                                              u16* __restrict__ xh, u16* __restrict__ xl) {
  __shared__ float tile[32 * 257];
  long t0 = (long)blockIdx.x * 32;
  int lb = (int)(t0 >> 13);
  int s0 = (int)(t0 & 8191);
  int tid = threadIdx.x;
  int ls = tid & 31;
  int half = (tid >> 5) & 1;      // two cols per wave-instruction
  int wv = tid >> 6;
#pragma unroll 4
  for (int cg = 0; cg < 32; ++cg) {
    int col = cg * 8 + wv * 2 + half;
    int dir = col >> 7, cc = (col >> 6) & 1, n = col & 63;
    int spos = dir ? (Sc - 1 - (s0 + ls)) : (s0 + ls);
    float v = xs[((((long)dir * nb + lb) * Nc + n) * Sc + spos) * 2 + cc];
    tile[ls * 257 + col] = v;
  }
  __syncthreads();
  for (int j = 0; j < 32; ++j) {
    float v = tile[j * 257 + tid];
    u16 hi = f2bf(v);
    long lt = t0 + j;
    xh[lt * 256 + tid] = hi;
    xl[lt * 256 + tid] = f2bf(v - bf2f(hi));
  }
}

// out1 = bf16( x + g1*(xs@G + h@P2 + pb) )
__global__ __launch_bounds__(256) void k_gemm_y(const u16* __restrict__ xh, const u16* __restrict__ xl,
                                                const u16* __restrict__ Gp,
                                                const u16* __restrict__ h, const u16* __restrict__ P2p,
                                                const void* __restrict__ xraw, long tok_base, int b0,
                                                const int* __restrict__ flag,
                                                const float* __restrict__ mods, const float* __restrict__ pb,
                                                u16* __restrict__ out1) {
  __shared__ Smem sm;
  f32x4 acc[4][4] = {};
  int bx, by; xcd_swz(bx, by);
  long row0 = (long)by * 128;
  int col0 = bx << 7;
  mfma_gemm(sm, xh, row0, 256, Gp, Fc, col0, acc);
  mfma_gemm(sm, xl, row0, 256, Gp, Fc, col0, acc);
  mfma_gemm(sm, h, row0, Fc, P2p, Fc, col0, acc);
  int bf = *flag;
  const int l = threadIdx.x & 63, q = l >> 4, li = l & 15;
  const int w = threadIdx.x >> 6;
  const int wm = (w >> 1) << 6, wn = (w & 1) << 6;
#pragma unroll
  for (int mt = 0; mt < 4; ++mt) {
#pragma unroll
    for (int r = 0; r < 4; ++r) {
      long lt = row0 + wm + (mt << 4) + (q << 2) + r;
      int b = b0 + (int)(lt >> 13);
      const float* mb = mods + b * SIXF + 2 * Fc;
#pragma unroll
      for (int nt = 0; nt < 4; ++nt) {
        int col = col0 + wn + (nt << 4) + li;
        float xv = ldf(xraw, (tok_base + lt) * Fc + col, bf);
        out1[lt * Fc + col] = f2bf(xv + mb[col] * (acc[mt][nt][r] + pb[col]));
      }
    }
  }
}

__device__ __forceinline__ float gelu_t(float u) {
  float inner = 0.7978845608028654f * fmaf(0.044715f * u * u, u, u);
  return 0.5f * u * (1.f + tanhf(inner));
}

__global__ __launch_bounds__(256) void k_mlp1(const u16* __restrict__ h2, const u16* __restrict__ W1p,
                                              const float* __restrict__ b1, long crow0,
                                              u16* __restrict__ tbuf) {
  __shared__ Smem sm;
  f32x4 acc[4][4] = {};
  int bx, by; xcd_swz(bx, by);
  long row0 = crow0 + (long)by * 128;
  int col0 = bx << 7;
  mfma_gemm(sm, h2, row0, Fc, W1p, Hc, col0, acc);
  const int l = threadIdx.x & 63, q = l >> 4, li = l & 15;
  const int w = threadIdx.x >> 6;
  const int wm = (w >> 1) << 6, wn = (w & 1) << 6;
#pragma unroll
  for (int mt = 0; mt < 4; ++mt) {
#pragma unroll
    for (int r = 0; r < 4; ++r) {
      long lr2 = row0 - crow0 + wm + (mt << 4) + (q << 2) + r;
#pragma unroll
      for (int nt = 0; nt < 4; ++nt) {
        int col = col0 + wn + (nt << 4) + li;
        tbuf[lr2 * Hc + col] = f2bf(gelu_t(acc[mt][nt][r] + b1[col]));
      }
    }
  }
}

__global__ __launch_bounds__(256) void k_mlp2(const u16* __restrict__ tbuf, const u16* __restrict__ W2p,
                                              const float* __restrict__ b2, const u16* __restrict__ out1,
                                              const float* __restrict__ mods, long crow0,
                                              long tok_base, int b0,
                                              const int* __restrict__ flag, void* __restrict__ dout) {
  __shared__ Smem sm;
  f32x4 acc[4][4] = {};
  int bx, by; xcd_swz(bx, by);
  long lrow0 = (long)by * 128;
  int col0 = bx << 7;
  mfma_gemm(sm, tbuf, lrow0, Hc, W2p, Fc, col0, acc);
  int bf = *flag;
  const int l = threadIdx.x & 63, q = l >> 4, li = l & 15;
  const int w = threadIdx.x >> 6;
  const int wm = (w >> 1) << 6, wn = (w & 1) << 6;
#pragma unroll
  for (int mt = 0; mt < 4; ++mt) {
#pragma unroll
    for (int r = 0; r < 4; ++r) {
      long lt = crow0 + lrow0 + wm + (mt << 4) + (q << 2) + r;
      int b = b0 + (int)(lt >> 13);
      const float* mb = mods + b * SIXF + 5 * Fc;
#pragma unroll
      for (int nt = 0; nt < 4; ++nt) {
        int col = col0 + wn + (nt << 4) + li;
        float v = bf2f(out1[lt * Fc + col]) + mb[col] * (acc[mt][nt][r] + b2[col]);
        long oi = (tok_base + lt) * Fc + col;
        if (bf) ((u16*)dout)[oi] = f2bf(v);
        else    ((float*)dout)[oi] = v;
      }
    }
  }
}

extern "C" void kernel_launch(void* const* d_in, const int* in_sizes, int n_in,
                              void* d_out, int out_size, void* d_ws, size_t ws_size,
                              hipStream_t stream) {
  char* ws = (char*)d_ws;
  size_t off = 0;
  auto alloc = [&](size_t bytes) -> char* {
    char* p = ws + off;
    off += (bytes + 255) & ~(size_t)255;
    return p;
  };
  int*   flag = (int*)  alloc(4);
  float* mods = (float*)alloc((size_t)Bc * SIXF * 4);
  float* Abar = (float*)alloc(2 * Nc * 2 * 4);
  float* pbf  = (float*)alloc(Fc * 4);
  float* b1f  = (float*)alloc(Hc * 4);
  float* b2f  = (float*)alloc(Fc * 4);
  u16* Wbup = (u16*)alloc((size_t)Fc * 256 * 2);
  u16* Gp   = (u16*)alloc((size_t)256 * Fc * 2);
  u16* P2p  = (u16*)alloc((size_t)Fc * Fc * 2);
  u16* W1p  = (u16*)alloc((size_t)Fc * Hc * 2);
  u16* W2p  = (u16*)alloc((size_t)Hc * Fc * 2);
  u16* pwp  = (u16*)alloc((size_t)1024 * Fc * 2);
  u16* Cpm  = (u16*)alloc((size_t)256 * Fc * 2);
  size_t off_static = off;

  const size_t U = (size_t)Sc * Fc * 2;   // 8.39 MB per batch unit
  int nb = 4;
  while (nb > 1 && off_static + (size_t)nb * 4 * U + 4096 > ws_size) nb >>= 1;

  u16*   h    = (u16*)  alloc((size_t)nb * U);
  float* Bu   = (float*)alloc((size_t)nb * U);
  u16*   xh   = (u16*)  alloc((size_t)nb * U / 2);
  u16*   xl   = (u16*)  alloc((size_t)nb * U / 2);
  u16*   out1 = (u16*)  alloc((size_t)nb * U);
  // MLP phase overlays (all producers of these regions are dead by then):
  //   h2   -> h region   (h dead after k_gemm_y)
  //   tbuf -> Bu+xh+xl   (2*nb*U bytes contiguous; Bu/xh/xl dead after k_gemm_y)
  // tbuf holds one half-row chunk: (rows/2)*Hc*2 = nb*U*2 bytes exactly.
  u16* tch = (u16*)Bu;
  u16* h2  = h;

  // detection + scalar conversions
  k_detect<<<1, 64, 0, stream>>>((const u16*)d_in[0], flag);
  k_convert<<<2, 256, 0, stream>>>(d_in[19], pbf, Fc, flag);
  k_convert<<<8, 256, 0, stream>>>(d_in[23], b1f, Hc, flag);
  k_convert<<<2, 256, 0, stream>>>(d_in[25], b2f, Fc, flag);
  // mods
  k_mods_init<<<12, 256, 0, stream>>>(d_in[21], flag, mods);
  k_mods2<<<dim3(12, Bc, 4), 256, 0, stream>>>(d_in[1], d_in[20], flag, mods);
  // S5 weights
  k_prep<<<dim3(2, 8), 64, 0, stream>>>(d_in[2], d_in[3], d_in[4], d_in[5], d_in[9],
                                        d_in[10], d_in[11], d_in[12], d_in[13], d_in[17],
                                        flag, Wbup, Abar);
  k_P2p<<<(Fc * Fc) / 256, 256, 0, stream>>>(d_in[8], d_in[16], d_in[18], flag, P2p);
  // G via MFMA: pack proj_w (1024x512) + build Cpm, then GEMM
  k_Wpack<<<256, 256, 0, stream>>>(d_in[18], flag, 9, pwp);
  k_Cpm<<<256, 256, 0, stream>>>(d_in[6], d_in[7], d_in[14], d_in[15], flag, Cpm);
  k_Gp2<<<dim3(4, 2), 256, 0, stream>>>(Cpm, pwp, Gp);
  // MLP weights
  k_Wpack<<<512, 256, 0, stream>>>(d_in[22], flag, 11, W1p);
  k_Wpack<<<512, 256, 0, stream>>>(d_in[24], flag, 9, W2p);

  for (int b0 = 0; b0 < Bc; b0 += nb) {
    long tok_base = (long)b0 * Sc;
    long rows = (long)nb * Sc;
    k_ln<<<rows, 256, 0, stream>>>(d_in[0], 0, tok_base, b0, flag, mods, 0, Fc, h);
    k_gemm_bu<<<dim3(2, rows / 128), 256, 0, stream>>>(h, Wbup, nb, Bu);
    k_scan<<<2 * nb * 64, 256, 0, stream>>>(Bu, Abar, nb);
    k_xs_t<<<rows / 32, 256, 0, stream>>>(Bu, nb, xh, xl);
    k_gemm_y<<<dim3(Fc / 128, rows / 128), 256, 0, stream>>>(xh, xl, Gp, h, P2p,
                                                             d_in[0], tok_base, b0, flag, mods, pbf, out1);
    k_ln<<<rows, 256, 0, stream>>>(out1, 1, 0, b0, flag, mods, 3 * Fc, 4 * Fc, h2);
    long RC = rows / 2;                  // 2 chunks: doubles mlp grids vs 4-chunk version
    for (int ch = 0; ch < 2; ++ch) {
      long crow0 = ch * RC;
      k_mlp1<<<dim3(Hc / 128, RC / 128), 256, 0, stream>>>(h2, W1p, b1f, crow0, tch);
      k_mlp2<<<dim3(Fc / 128, RC / 128), 256, 0, stream>>>(tch, W2p, b2f, out1, mods, crow0,
                                                           tok_base, b0, flag, d_out);
    }
  }
  (void)n_in; (void)out_size; (void)in_sizes;
}

// Round 3
// 667.849 us; speedup vs baseline: 1.2490x; 1.0289x over previous
//
#include <hip/hip_runtime.h>
#include <hip/hip_bf16.h>

typedef unsigned short u16;
typedef __attribute__((ext_vector_type(8))) short bf16x8;
typedef __attribute__((ext_vector_type(4))) float f32x4;

#define Bc 4
#define Sc 8192
#define Fc 512
#define Nc 64
#define Hc 2048
#define Tc 32768
#define SIXF 3072

__device__ __forceinline__ u16 f2bf(float v) {
  __hip_bfloat16 h = __float2bfloat16(v);
  return *reinterpret_cast<u16*>(&h);
}
__device__ __forceinline__ float bf2f(u16 u) {
  return __uint_as_float(((unsigned)u) << 16);
}
__device__ __forceinline__ float ldf(const void* p, long i, int bf) {
  return bf ? bf2f(((const u16*)p)[i]) : ((const float*)p)[i];
}

// async global->LDS, 16 bytes per lane. LDS dest is wave-uniform base + lane*16.
__device__ __forceinline__ void ld16(const u16* g, u16* l) {
  __builtin_amdgcn_global_load_lds(
      (const __attribute__((address_space(1))) unsigned int*)g,
      (__attribute__((address_space(3))) unsigned int*)l,
      16, 0, 0);
}

// XCD-aware bijective block remap (valid when nwg % 8 == 0; identity otherwise).
__device__ __forceinline__ void xcd_swz(int& bx, int& by) {
  int gx = gridDim.x;
  int nwg = gx * gridDim.y;
  int lin = blockIdx.x + gx * blockIdx.y;
  if ((nwg & 7) == 0) {
    int q = nwg >> 3;
    lin = (lin & 7) * q + (lin >> 3);
  }
  bx = lin % gx;
  by = lin / gx;
}

// ---------- dtype detection ----------
__global__ void k_detect(const u16* __restrict__ x, int* __restrict__ flag) {
  if (threadIdx.x == 0) {
    int cnt = 0;
    for (int i = 0; i < 256; ++i) {
      int e = (x[i] >> 7) & 0xFF;
      cnt += (e >= 130);
    }
    *flag = (cnt >= 16) ? 0 : 1;   // 1 = bf16 inputs, 0 = fp32
  }
}

__global__ void k_convert(const void* __restrict__ src, float* __restrict__ dst,
                          int n, const int* __restrict__ flag) {
  int bf = *flag;
  int i = blockIdx.x * blockDim.x + threadIdx.x;
  int stride = gridDim.x * blockDim.x;
  for (int j = i; j < n; j += stride) dst[j] = ldf(src, j, bf);
}

// ---------- mods: init with ada_b, then f-chunked atomic accumulation ----------
__global__ __launch_bounds__(256) void k_mods_init(const void* __restrict__ ada_b,
                                                   const int* __restrict__ flag,
                                                   float* __restrict__ mods) {
  int bf = *flag;
  int col = blockIdx.x * 256 + threadIdx.x;   // grid 12
  float v = ldf(ada_b, col, bf);
  for (int b = 0; b < Bc; ++b) mods[b * SIXF + col] = v;
}

__global__ __launch_bounds__(256) void k_mods2(const void* __restrict__ cond,
                                               const void* __restrict__ ada_w,
                                               const int* __restrict__ flag,
                                               float* __restrict__ mods) {
  int bf = *flag;
  int b = blockIdx.y;
  int f0 = blockIdx.z * 128;
  int col = blockIdx.x * 256 + threadIdx.x;
  __shared__ float sc[128];
  for (int i = threadIdx.x; i < 128; i += 256) {
    float c = ldf(cond, b * Fc + f0 + i, bf);
    sc[i] = c / (1.f + expf(-c));
  }
  __syncthreads();
  float acc = 0.f;
  for (int f = 0; f < 128; ++f) acc = fmaf(sc[f], ldf(ada_w, (long)(f0 + f) * SIXF + col, bf), acc);
  atomicAdd(&mods[b * SIXF + col], acc);
}

// ---------- Abar + Wbu packed, f-chunked ----------
__global__ void k_prep(const void* lAf, const void* Aif, const void* Brf, const void* Bif, const void* ldtf,
                       const void* lAb, const void* Aib, const void* Brb, const void* Bib, const void* ldtb,
                       const int* __restrict__ flag,
                       u16* __restrict__ Wbup, float* __restrict__ Abar) {
  int bf = *flag;
  int dir = blockIdx.x;
  int f0 = blockIdx.y * 64;     // grid (2, 8)
  int n = threadIdx.x;          // 64
  const void* lA = dir ? lAb : lAf;
  const void* Ai = dir ? Aib : Aif;
  const void* Br = dir ? Brb : Brf;
  const void* Bi = dir ? Bib : Bif;
  const void* ld = dir ? ldtb : ldtf;
  float dt  = expf(ldf(ld, n, bf));
  float Are = -expf(ldf(lA, n, bf));
  float Aim = ldf(Ai, n, bf);
  float er  = expf(Are * dt);
  float abr = er * cosf(Aim * dt);
  float abi = er * sinf(Aim * dt);
  if (blockIdx.y == 0) {
    Abar[(dir * Nc + n) * 2 + 0] = abr;
    Abar[(dir * Nc + n) * 2 + 1] = abi;
  }
  float dr = Are + 1e-8f, di = Aim;
  float den = dr * dr + di * di;
  float nr = abr - 1.f, ni = abi;
  float cr = (nr * dr + ni * di) / den;
  float ci = (ni * dr - nr * di) / den;
  int col_re = dir * 128 + n, col_im = dir * 128 + 64 + n;
  for (int f = f0; f < f0 + 64; ++f) {
    float br = ldf(Br, n * Fc + f, bf), bi = ldf(Bi, n * Fc + f, bf);
    Wbup[(((f >> 3) * 256) + col_re) * 8 + (f & 7)] = f2bf(cr * br - ci * bi);
    Wbup[(((f >> 3) * 256) + col_im) * 8 + (f & 7)] = f2bf(cr * bi + ci * br);
  }
}

// P2 packed bf16 [512/8][512][8]
__global__ __launch_bounds__(256) void k_P2p(const void* Df, const void* Db, const void* pw,
                                             const int* __restrict__ flag, u16* __restrict__ P2p) {
  int bf = *flag;
  int idx = blockIdx.x * 256 + threadIdx.x;
  int f1 = idx >> 9, fo = idx & 511;
  float v = ldf(Df, f1, bf) * ldf(pw, (long)f1 * Fc + fo, bf) +
            ldf(Db, f1, bf) * ldf(pw, (long)(Fc + f1) * Fc + fo, bf);
  P2p[(((f1 >> 3) * Fc) + fo) * 8 + (f1 & 7)] = f2bf(v);
}

// Cpm bf16 [256][512]: row k=dir*128+c*64+n, Cpm[k][f] = (+Cre|-Cim)[f][n]
__global__ __launch_bounds__(256) void k_Cpm(const void* Cref, const void* Cimf,
                                             const void* Creb, const void* Cimb,
                                             const int* __restrict__ flag, u16* __restrict__ Cpm) {
  int bf = *flag;
  int k = blockIdx.x;
  int dir = k >> 7, c = (k >> 6) & 1, n = k & 63;
  const void* C = dir ? (c ? Cimb : Creb) : (c ? Cimf : Cref);
  float sgn = c ? -1.f : 1.f;
  for (int f = threadIdx.x; f < Fc; f += 256)
    Cpm[k * Fc + f] = f2bf(sgn * ldf(C, (long)f * Nc + n, bf));
}

// generic raw [K,N] -> packed bf16 [K/8][N][8]; one thread per (k8,n)
__global__ __launch_bounds__(256) void k_Wpack(const void* __restrict__ src, const int* __restrict__ flag,
                                               int log2N, u16* __restrict__ dst) {
  int bf = *flag;
  long i = (long)blockIdx.x * 256 + threadIdx.x;     // over (K/8)*N
  int Nn = 1 << log2N;
  long k8 = i >> log2N;
  int n = (int)(i & (Nn - 1));
  u16 tmp[8];
#pragma unroll
  for (int j = 0; j < 8; ++j)
    tmp[j] = f2bf(ldf(src, ((k8 << 3) + j) * (long)Nn + n, bf));
  *(ushort4*)(dst + i * 8)     = *(ushort4*)tmp;
  *(ushort4*)(dst + i * 8 + 4) = *(ushort4*)(tmp + 4);
}

// ---------- LayerNorm + AdaLN ----------
__global__ __launch_bounds__(256) void k_ln(const void* __restrict__ src, int srcmode,
                                            long src_tok_base, int b0,
                                            const int* __restrict__ flag,
                                            const float* __restrict__ mods,
                                            int sh_base, int sc_base,
                                            u16* __restrict__ dst) {
  int bf = srcmode ? 1 : *flag;
  long lt = blockIdx.x;
  int b = b0 + (int)(lt >> 13);
  int t = threadIdx.x;
  long si = (src_tok_base + lt) * Fc;
  float x0 = ldf(src, si + t, bf);
  float x1 = ldf(src, si + t + 256, bf);
  float s = x0 + x1, qq = x0 * x0 + x1 * x1;
  for (int o = 32; o; o >>= 1) { s += __shfl_down(s, o); qq += __shfl_down(qq, o); }
  __shared__ float ss[4], sq[4];
  int w = t >> 6;
  if ((t & 63) == 0) { ss[w] = s; sq[w] = qq; }
  __syncthreads();
  float S = ss[0] + ss[1] + ss[2] + ss[3];
  float Q = sq[0] + sq[1] + sq[2] + sq[3];
  float mu = S * (1.f / Fc);
  float var = Q * (1.f / Fc) - mu * mu;
  float rs = rsqrtf(var + 1e-5f);
  const float* mb = mods + b * SIXF;
  float h0 = (x0 - mu) * rs * (1.f + mb[sc_base + t]) + mb[sh_base + t];
  float h1 = (x1 - mu) * rs * (1.f + mb[sc_base + t + 256]) + mb[sh_base + t + 256];
  dst[lt * Fc + t] = f2bf(h0);
  dst[lt * Fc + t + 256] = f2bf(h1);
}

// ---------- MFMA GEMM core ----------
// A staged via global_load_lds with PRE-SWIZZLED global source (linear LDS dest,
// XOR-swizzled read): LDS chunk c holds A[m][kc] with m=c>>3, kc=(c&7)^(m&7).
// W staged linearly. 16B per lane per issue.
struct Smem { u16 As[128 * 64]; u16 Ws[64 * 128]; };

__device__ __forceinline__ void mfma_gemm(Smem& sm, const u16* __restrict__ A, long row0, int K,
                                          const u16* __restrict__ Wp, int N, int col0,
                                          f32x4 (&acc)[4][4]) {
  const int tid = threadIdx.x;
  const int l = tid & 63;
  const int q = l >> 4, li = l & 15;
  const int w = tid >> 6;
  const int wm = (w >> 1) << 6, wn = (w & 1) << 6;
  // per-thread loop-invariant source offsets (elements)
  const int m0 = tid >> 3;
  const int kc0 = (tid & 7) ^ (m0 & 7);            // invariant under c += 256 (m += 32)
  const long aoff0 = (row0 + m0) * (long)K + (kc0 << 3);
  const long woff0 = (long)(tid >> 7) * ((long)N << 3) + ((long)(col0 + (tid & 127)) << 3);
  u16* asdst = sm.As + ((w << 6) << 3);            // wave-uniform LDS base
  u16* wsdst = sm.Ws + ((w << 6) << 3);
  for (int k0 = 0; k0 < K; k0 += 64) {
    __syncthreads();
#pragma unroll
    for (int it = 0; it < 4; ++it)
      ld16(A + aoff0 + (long)it * ((long)K << 5) + k0, asdst + (it << 11));
#pragma unroll
    for (int it = 0; it < 4; ++it)
      ld16(Wp + woff0 + (long)k0 * N + (long)it * ((long)N << 4), wsdst + (it << 11));
    __syncthreads();
#pragma unroll
    for (int ks = 0; ks < 2; ++ks) {
      bf16x8 af[4], bw[4];
#pragma unroll
      for (int mt = 0; mt < 4; ++mt) {
        int mrow = wm + (mt << 4) + li;
        af[mt] = *(const bf16x8*)(sm.As + (((mrow << 3) + (((ks << 2) + q) ^ (mrow & 7))) << 3));
      }
#pragma unroll
      for (int nt = 0; nt < 4; ++nt) {
        int n = wn + (nt << 4) + li;
        bw[nt] = *(const bf16x8*)(sm.Ws + ((((((ks << 2) + q) << 7) + n)) << 3));
      }
#pragma unroll
      for (int mt = 0; mt < 4; ++mt)
#pragma unroll
        for (int nt = 0; nt < 4; ++nt)
          acc[mt][nt] = __builtin_amdgcn_mfma_f32_16x16x32_bf16(af[mt], bw[nt], acc[mt][nt], 0, 0, 0);
    }
  }
}

// G via MFMA: Cpm[256,512] @ pwp(dir half) -> packed Gp
__global__ __launch_bounds__(256) void k_Gp2(const u16* __restrict__ Cpm, const u16* __restrict__ pwp,
                                             u16* __restrict__ Gp) {
  __shared__ Smem sm;
  f32x4 acc[4][4] = {};
  int bx, by; xcd_swz(bx, by);
  long row0 = (long)by * 128;
  int col0 = bx << 7;
  int dir = (int)(row0 >> 7);
  mfma_gemm(sm, Cpm, row0, Fc, pwp + (size_t)dir * 262144, Fc, col0, acc);
  const int l = threadIdx.x & 63, q = l >> 4, li = l & 15;
  const int w = threadIdx.x >> 6;
  const int wm = (w >> 1) << 6, wn = (w & 1) << 6;
#pragma unroll
  for (int mt = 0; mt < 4; ++mt)
#pragma unroll
    for (int nt = 0; nt < 4; ++nt)
#pragma unroll
      for (int r = 0; r < 4; ++r) {
        int k = (int)row0 + wm + (mt << 4) + (q << 2) + r;
        int col = col0 + wn + (nt << 4) + li;
        Gp[(((k >> 3) * Fc) + col) * 8 + (k & 7)] = f2bf(acc[mt][nt][r]);
      }
}

// Bu GEMM: h[nb*8192,512] @ Wbu -> Bu[dir][lb][n][s][2] (bwd s flipped)
__global__ __launch_bounds__(256) void k_gemm_bu(const u16* __restrict__ h,
                                                 const u16* __restrict__ Wbup,
                                                 int nb, float* __restrict__ Bu) {
  __shared__ Smem sm;
  f32x4 acc[4][4] = {};
  int bx, by; xcd_swz(bx, by);
  long row0 = (long)by * 128;
  int col0 = bx << 7;
  mfma_gemm(sm, h, row0, Fc, Wbup, 256, col0, acc);
  const int l = threadIdx.x & 63, q = l >> 4, li = l & 15;
  const int w = threadIdx.x >> 6;
  const int wm = (w >> 1) << 6, wn = (w & 1) << 6;
#pragma unroll
  for (int mt = 0; mt < 4; ++mt) {
#pragma unroll
    for (int nt = 0; nt < 4; ++nt) {
      int col = col0 + wn + (nt << 4) + li;
      int dir = col >> 7, cc = (col >> 6) & 1, n = col & 63;
#pragma unroll
      for (int r = 0; r < 4; ++r) {
        long lt = row0 + wm + (mt << 4) + (q << 2) + r;
        int lb = (int)(lt >> 13), s = (int)(lt & 8191);
        int spos = dir ? (Sc - 1 - s) : s;
        Bu[((((long)dir * nb + lb) * Nc + n) * Sc + spos) * 2 + cc] = acc[mt][nt][r];
      }
    }
  }
}

// chunked complex linear scan, in-place on Bu (float4 I/O). One block per (dir,lb,n).
__global__ __launch_bounds__(256) void k_scan(float* __restrict__ Bu, const float* __restrict__ Abar,
                                              int nb) {
  int blk = blockIdx.x;
  int per_dir = nb * 64;
  int dir = blk / per_dir;
  int rem = blk - dir * per_dir;
  int lb = rem >> 6, n = rem & 63;
  float ar = Abar[(dir * Nc + n) * 2 + 0];
  float ai = Abar[(dir * Nc + n) * 2 + 1];
  float* base = Bu + (((long)dir * nb + lb) * Nc + n) * Sc * 2;
  int t = threadIdx.x;
  float4 loc[16];
  float lr = 0.f, li = 0.f;
  const float4* bp = (const float4*)base + t * 16;
#pragma unroll
  for (int j = 0; j < 16; ++j) {
    float4 v = bp[j];
    loc[j] = v;
    float nr = fmaf(ar, lr, fmaf(-ai, li, v.x));
    float ni = fmaf(ar, li, fmaf(ai, lr, v.y));
    lr = fmaf(ar, nr, fmaf(-ai, ni, v.z));
    li = fmaf(ar, ni, fmaf(ai, nr, v.w));
  }
  __shared__ float sr[256], si[256];
  float pr = ar, pi = ai;
  for (int k = 0; k < 5; ++k) { float t2 = pr * pr - pi * pi; pi = 2.f * pr * pi; pr = t2; }  // a^32
  float vr = lr, vi = li;
  for (int step = 1; step < 256; step <<= 1) {
    sr[t] = vr; si[t] = vi;
    __syncthreads();
    if (t >= step) {
      float orr = sr[t - step], oii = si[t - step];
      vr = vr + pr * orr - pi * oii;
      vi = vi + pr * oii + pi * orr;
    }
    __syncthreads();
    float t2 = pr * pr - pi * pi; pi = 2.f * pr * pi; pr = t2;
  }
  sr[t] = vr; si[t] = vi;
  __syncthreads();
  float xr = (t == 0) ? 0.f : sr[t - 1];
  float xi = (t == 0) ? 0.f : si[t - 1];
  float4* op = (float4*)base + t * 16;
#pragma unroll
  for (int j = 0; j < 16; ++j) {
    float4 v = loc[j];
    float nr = fmaf(ar, xr, fmaf(-ai, xi, v.x));
    float ni = fmaf(ar, xi, fmaf(ai, xr, v.y));
    xr = fmaf(ar, nr, fmaf(-ai, ni, v.z));
    xi = fmaf(ar, ni, fmaf(ai, nr, v.w));
    float4 o; o.x = nr; o.y = ni; o.z = xr; o.w = xi;
    op[j] = o;
  }
}

// gather xs -> token-major bf16 hi/lo via LDS transpose (32 tokens x 256 cols per block)
__global__ __launch_bounds__(256) void k_xs_t(const float* __restrict__ xs, int nb,
                                              u16* __restrict__ xh, u16* __restrict__ xl) {
  __shared__ float tile[32 * 257];
  long t0 = (long)blockIdx.x * 32;
  int lb = (int)(t0 >> 13);
  int s0 = (int)(t0 & 8191);
  int tid = threadIdx.x;
  int ls = tid & 31;
  int half = (tid >> 5) & 1;      // two cols per wave-instruction
  int wv = tid >> 6;
#pragma unroll 4
  for (int cg = 0; cg < 32; ++cg) {
    int col = cg * 8 + wv * 2 + half;
    int dir = col >> 7, cc = (col >> 6) & 1, n = col & 63;
    int spos = dir ? (Sc - 1 - (s0 + ls)) : (s0 + ls);
    float v = xs[((((long)dir * nb + lb) * Nc + n) * Sc + spos) * 2 + cc];
    tile[ls * 257 + col] = v;
  }
  __syncthreads();
  for (int j = 0; j < 32; ++j) {
    float v = tile[j * 257 + tid];
    u16 hi = f2bf(v);
    long lt = t0 + j;
    xh[lt * 256 + tid] = hi;
    xl[lt * 256 + tid] = f2bf(v - bf2f(hi));
  }
}

// out1 = bf16( x + g1*(xs@G + h@P2 + pb) )
__global__ __launch_bounds__(256) void k_gemm_y(const u16* __restrict__ xh, const u16* __restrict__ xl,
                                                const u16* __restrict__ Gp,
                                                const u16* __restrict__ h, const u16* __restrict__ P2p,
                                                const void* __restrict__ xraw, long tok_base, int b0,
                                                const int* __restrict__ flag,
                                                const float* __restrict__ mods, const float* __restrict__ pb,
                                                u16* __restrict__ out1) {
  __shared__ Smem sm;
  f32x4 acc[4][4] = {};
  int bx, by; xcd_swz(bx, by);
  long row0 = (long)by * 128;
  int col0 = bx << 7;
  mfma_gemm(sm, xh, row0, 256, Gp, Fc, col0, acc);
  mfma_gemm(sm, xl, row0, 256, Gp, Fc, col0, acc);
  mfma_gemm(sm, h, row0, Fc, P2p, Fc, col0, acc);
  int bf = *flag;
  const int l = threadIdx.x & 63, q = l >> 4, li = l & 15;
  const int w = threadIdx.x >> 6;
  const int wm = (w >> 1) << 6, wn = (w & 1) << 6;
#pragma unroll
  for (int mt = 0; mt < 4; ++mt) {
#pragma unroll
    for (int r = 0; r < 4; ++r) {
      long lt = row0 + wm + (mt << 4) + (q << 2) + r;
      int b = b0 + (int)(lt >> 13);
      const float* mb = mods + b * SIXF + 2 * Fc;
#pragma unroll
      for (int nt = 0; nt < 4; ++nt) {
        int col = col0 + wn + (nt << 4) + li;
        float xv = ldf(xraw, (tok_base + lt) * Fc + col, bf);
        out1[lt * Fc + col] = f2bf(xv + mb[col] * (acc[mt][nt][r] + pb[col]));
      }
    }
  }
}

// tanh-approx gelu via hardware exp2+rcp:
//   0.5*u*(1+tanh(z)) == u * sigmoid(2z);  sigmoid(2z) = 1/(1+exp(-2z))
//   exp(-2z) = exp2(-2*log2(e)*z) -> one v_exp_f32; 1/(1+e) -> one v_rcp_f32.
// ~8 VALU ops vs ~35 for library tanhf; error ~1ulp f32, far below bf16 rounding.
__device__ __forceinline__ float gelu_t(float u) {
  float z = 0.7978845608028654f * fmaf(0.044715f * u * u, u, u);
  float e = __builtin_amdgcn_exp2f(z * -2.8853900817779268f);   // exp(-2z)
  return u * __builtin_amdgcn_rcpf(1.f + e);
}

__global__ __launch_bounds__(256) void k_mlp1(const u16* __restrict__ h2, const u16* __restrict__ W1p,
                                              const float* __restrict__ b1, long crow0,
                                              u16* __restrict__ tbuf) {
  __shared__ Smem sm;
  f32x4 acc[4][4] = {};
  int bx, by; xcd_swz(bx, by);
  long row0 = crow0 + (long)by * 128;
  int col0 = bx << 7;
  mfma_gemm(sm, h2, row0, Fc, W1p, Hc, col0, acc);
  const int l = threadIdx.x & 63, q = l >> 4, li = l & 15;
  const int w = threadIdx.x >> 6;
  const int wm = (w >> 1) << 6, wn = (w & 1) << 6;
#pragma unroll
  for (int mt = 0; mt < 4; ++mt) {
#pragma unroll
    for (int r = 0; r < 4; ++r) {
      long lr2 = row0 - crow0 + wm + (mt << 4) + (q << 2) + r;
#pragma unroll
      for (int nt = 0; nt < 4; ++nt) {
        int col = col0 + wn + (nt << 4) + li;
        tbuf[lr2 * Hc + col] = f2bf(gelu_t(acc[mt][nt][r] + b1[col]));
      }
    }
  }
}

__global__ __launch_bounds__(256) void k_mlp2(const u16* __restrict__ tbuf, const u16* __restrict__ W2p,
                                              const float* __restrict__ b2, const u16* __restrict__ out1,
                                              const float* __restrict__ mods, long crow0,
                                              long tok_base, int b0,
                                              const int* __restrict__ flag, void* __restrict__ dout) {
  __shared__ Smem sm;
  f32x4 acc[4][4] = {};
  int bx, by; xcd_swz(bx, by);
  long lrow0 = (long)by * 128;
  int col0 = bx << 7;
  mfma_gemm(sm, tbuf, lrow0, Hc, W2p, Fc, col0, acc);
  int bf = *flag;
  const int l = threadIdx.x & 63, q = l >> 4, li = l & 15;
  const int w = threadIdx.x >> 6;
  const int wm = (w >> 1) << 6, wn = (w & 1) << 6;
#pragma unroll
  for (int mt = 0; mt < 4; ++mt) {
#pragma unroll
    for (int r = 0; r < 4; ++r) {
      long lt = crow0 + lrow0 + wm + (mt << 4) + (q << 2) + r;
      int b = b0 + (int)(lt >> 13);
      const float* mb = mods + b * SIXF + 5 * Fc;
#pragma unroll
      for (int nt = 0; nt < 4; ++nt) {
        int col = col0 + wn + (nt << 4) + li;
        float v = bf2f(out1[lt * Fc + col]) + mb[col] * (acc[mt][nt][r] + b2[col]);
        long oi = (tok_base + lt) * Fc + col;
        if (bf) ((u16*)dout)[oi] = f2bf(v);
        else    ((float*)dout)[oi] = v;
      }
    }
  }
}

extern "C" void kernel_launch(void* const* d_in, const int* in_sizes, int n_in,
                              void* d_out, int out_size, void* d_ws, size_t ws_size,
                              hipStream_t stream) {
  char* ws = (char*)d_ws;
  size_t off = 0;
  auto alloc = [&](size_t bytes) -> char* {
    char* p = ws + off;
    off += (bytes + 255) & ~(size_t)255;
    return p;
  };
  int*   flag = (int*)  alloc(4);
  float* mods = (float*)alloc((size_t)Bc * SIXF * 4);
  float* Abar = (float*)alloc(2 * Nc * 2 * 4);
  float* pbf  = (float*)alloc(Fc * 4);
  float* b1f  = (float*)alloc(Hc * 4);
  float* b2f  = (float*)alloc(Fc * 4);
  u16* Wbup = (u16*)alloc((size_t)Fc * 256 * 2);
  u16* Gp   = (u16*)alloc((size_t)256 * Fc * 2);
  u16* P2p  = (u16*)alloc((size_t)Fc * Fc * 2);
  u16* W1p  = (u16*)alloc((size_t)Fc * Hc * 2);
  u16* W2p  = (u16*)alloc((size_t)Hc * Fc * 2);
  u16* pwp  = (u16*)alloc((size_t)1024 * Fc * 2);
  u16* Cpm  = (u16*)alloc((size_t)256 * Fc * 2);
  size_t off_static = off;

  const size_t U = (size_t)Sc * Fc * 2;   // 8.39 MB per batch unit
  int nb = 4;
  while (nb > 1 && off_static + (size_t)nb * 4 * U + 4096 > ws_size) nb >>= 1;

  u16*   h    = (u16*)  alloc((size_t)nb * U);
  float* Bu   = (float*)alloc((size_t)nb * U);
  u16*   xh   = (u16*)  alloc((size_t)nb * U / 2);
  u16*   xl   = (u16*)  alloc((size_t)nb * U / 2);
  u16*   out1 = (u16*)  alloc((size_t)nb * U);
  // MLP phase overlays (all producers of these regions are dead by then):
  //   h2   -> h region   (h dead after k_gemm_y)
  //   tbuf -> Bu+xh+xl   (2*nb*U bytes contiguous; Bu/xh/xl dead after k_gemm_y)
  // tbuf holds one half-row chunk: (rows/2)*Hc*2 = nb*U*2 bytes exactly.
  u16* tch = (u16*)Bu;
  u16* h2  = h;

  // detection + scalar conversions
  k_detect<<<1, 64, 0, stream>>>((const u16*)d_in[0], flag);
  k_convert<<<2, 256, 0, stream>>>(d_in[19], pbf, Fc, flag);
  k_convert<<<8, 256, 0, stream>>>(d_in[23], b1f, Hc, flag);
  k_convert<<<2, 256, 0, stream>>>(d_in[25], b2f, Fc, flag);
  // mods
  k_mods_init<<<12, 256, 0, stream>>>(d_in[21], flag, mods);
  k_mods2<<<dim3(12, Bc, 4), 256, 0, stream>>>(d_in[1], d_in[20], flag, mods);
  // S5 weights
  k_prep<<<dim3(2, 8), 64, 0, stream>>>(d_in[2], d_in[3], d_in[4], d_in[5], d_in[9],
                                        d_in[10], d_in[11], d_in[12], d_in[13], d_in[17],
                                        flag, Wbup, Abar);
  k_P2p<<<(Fc * Fc) / 256, 256, 0, stream>>>(d_in[8], d_in[16], d_in[18], flag, P2p);
  // G via MFMA: pack proj_w (1024x512) + build Cpm, then GEMM
  k_Wpack<<<256, 256, 0, stream>>>(d_in[18], flag, 9, pwp);
  k_Cpm<<<256, 256, 0, stream>>>(d_in[6], d_in[7], d_in[14], d_in[15], flag, Cpm);
  k_Gp2<<<dim3(4, 2), 256, 0, stream>>>(Cpm, pwp, Gp);
  // MLP weights
  k_Wpack<<<512, 256, 0, stream>>>(d_in[22], flag, 11, W1p);
  k_Wpack<<<512, 256, 0, stream>>>(d_in[24], flag, 9, W2p);

  for (int b0 = 0; b0 < Bc; b0 += nb) {
    long tok_base = (long)b0 * Sc;
    long rows = (long)nb * Sc;
    k_ln<<<rows, 256, 0, stream>>>(d_in[0], 0, tok_base, b0, flag, mods, 0, Fc, h);
    k_gemm_bu<<<dim3(2, rows / 128), 256, 0, stream>>>(h, Wbup, nb, Bu);
    k_scan<<<2 * nb * 64, 256, 0, stream>>>(Bu, Abar, nb);
    k_xs_t<<<rows / 32, 256, 0, stream>>>(Bu, nb, xh, xl);
    k_gemm_y<<<dim3(Fc / 128, rows / 128), 256, 0, stream>>>(xh, xl, Gp, h, P2p,
                                                             d_in[0], tok_base, b0, flag, mods, pbf, out1);
    k_ln<<<rows, 256, 0, stream>>>(out1, 1, 0, b0, flag, mods, 3 * Fc, 4 * Fc, h2);
    long RC = rows / 2;                  // 2 chunks: doubles mlp grids vs 4-chunk version
    for (int ch = 0; ch < 2; ++ch) {
      long crow0 = ch * RC;
      k_mlp1<<<dim3(Hc / 128, RC / 128), 256, 0, stream>>>(h2, W1p, b1f, crow0, tch);
      k_mlp2<<<dim3(Fc / 128, RC / 128), 256, 0, stream>>>(tch, W2p, b2f, out1, mods, crow0,
                                                           tok_base, b0, flag, d_out);
    }
  }
  (void)n_in; (void)out_size; (void)in_sizes;
}

// Round 4
// 639.460 us; speedup vs baseline: 1.3045x; 1.0444x over previous
//
#include <hip/hip_runtime.h>
#include <hip/hip_bf16.h>

typedef unsigned short u16;
typedef __attribute__((ext_vector_type(8))) short bf16x8;
typedef __attribute__((ext_vector_type(4))) float f32x4;

#define Bc 4
#define Sc 8192
#define Fc 512
#define Nc 64
#define Hc 2048
#define Tc 32768
#define SIXF 3072

__device__ __forceinline__ u16 f2bf(float v) {
  __hip_bfloat16 h = __float2bfloat16(v);
  return *reinterpret_cast<u16*>(&h);
}
__device__ __forceinline__ float bf2f(u16 u) {
  return __uint_as_float(((unsigned)u) << 16);
}
__device__ __forceinline__ float ldf(const void* p, long i, int bf) {
  return bf ? bf2f(((const u16*)p)[i]) : ((const float*)p)[i];
}

// async global->LDS, 16 bytes per lane. LDS dest is wave-uniform base + lane*16.
__device__ __forceinline__ void ld16(const u16* g, u16* l) {
  __builtin_amdgcn_global_load_lds(
      (const __attribute__((address_space(1))) unsigned int*)g,
      (__attribute__((address_space(3))) unsigned int*)l,
      16, 0, 0);
}

// XCD-aware bijective block remap (valid when nwg % 8 == 0; identity otherwise).
__device__ __forceinline__ void xcd_swz(int& bx, int& by) {
  int gx = gridDim.x;
  int nwg = gx * gridDim.y;
  int lin = blockIdx.x + gx * blockIdx.y;
  if ((nwg & 7) == 0) {
    int q = nwg >> 3;
    lin = (lin & 7) * q + (lin >> 3);
  }
  bx = lin % gx;
  by = lin / gx;
}

// ---------- dtype detection ----------
__global__ void k_detect(const u16* __restrict__ x, int* __restrict__ flag) {
  if (threadIdx.x == 0) {
    int cnt = 0;
    for (int i = 0; i < 256; ++i) {
      int e = (x[i] >> 7) & 0xFF;
      cnt += (e >= 130);
    }
    *flag = (cnt >= 16) ? 0 : 1;   // 1 = bf16 inputs, 0 = fp32
  }
}

__global__ void k_convert(const void* __restrict__ src, float* __restrict__ dst,
                          int n, const int* __restrict__ flag) {
  int bf = *flag;
  int i = blockIdx.x * blockDim.x + threadIdx.x;
  int stride = gridDim.x * blockDim.x;
  for (int j = i; j < n; j += stride) dst[j] = ldf(src, j, bf);
}

// ---------- mods: init with ada_b, then f-chunked atomic accumulation ----------
__global__ __launch_bounds__(256) void k_mods_init(const void* __restrict__ ada_b,
                                                   const int* __restrict__ flag,
                                                   float* __restrict__ mods) {
  int bf = *flag;
  int col = blockIdx.x * 256 + threadIdx.x;   // grid 12
  float v = ldf(ada_b, col, bf);
  for (int b = 0; b < Bc; ++b) mods[b * SIXF + col] = v;
}

__global__ __launch_bounds__(256) void k_mods2(const void* __restrict__ cond,
                                               const void* __restrict__ ada_w,
                                               const int* __restrict__ flag,
                                               float* __restrict__ mods) {
  int bf = *flag;
  int b = blockIdx.y;
  int f0 = blockIdx.z * 128;
  int col = blockIdx.x * 256 + threadIdx.x;
  __shared__ float sc[128];
  for (int i = threadIdx.x; i < 128; i += 256) {
    float c = ldf(cond, b * Fc + f0 + i, bf);
    sc[i] = c / (1.f + expf(-c));
  }
  __syncthreads();
  float acc = 0.f;
  for (int f = 0; f < 128; ++f) acc = fmaf(sc[f], ldf(ada_w, (long)(f0 + f) * SIXF + col, bf), acc);
  atomicAdd(&mods[b * SIXF + col], acc);
}

// ---------- Abar + Wbu packed, f-chunked ----------
__global__ void k_prep(const void* lAf, const void* Aif, const void* Brf, const void* Bif, const void* ldtf,
                       const void* lAb, const void* Aib, const void* Brb, const void* Bib, const void* ldtb,
                       const int* __restrict__ flag,
                       u16* __restrict__ Wbup, float* __restrict__ Abar) {
  int bf = *flag;
  int dir = blockIdx.x;
  int f0 = blockIdx.y * 64;     // grid (2, 8)
  int n = threadIdx.x;          // 64
  const void* lA = dir ? lAb : lAf;
  const void* Ai = dir ? Aib : Aif;
  const void* Br = dir ? Brb : Brf;
  const void* Bi = dir ? Bib : Bif;
  const void* ld = dir ? ldtb : ldtf;
  float dt  = expf(ldf(ld, n, bf));
  float Are = -expf(ldf(lA, n, bf));
  float Aim = ldf(Ai, n, bf);
  float er  = expf(Are * dt);
  float abr = er * cosf(Aim * dt);
  float abi = er * sinf(Aim * dt);
  if (blockIdx.y == 0) {
    Abar[(dir * Nc + n) * 2 + 0] = abr;
    Abar[(dir * Nc + n) * 2 + 1] = abi;
  }
  float dr = Are + 1e-8f, di = Aim;
  float den = dr * dr + di * di;
  float nr = abr - 1.f, ni = abi;
  float cr = (nr * dr + ni * di) / den;
  float ci = (ni * dr - nr * di) / den;
  int col_re = dir * 128 + n, col_im = dir * 128 + 64 + n;
  for (int f = f0; f < f0 + 64; ++f) {
    float br = ldf(Br, n * Fc + f, bf), bi = ldf(Bi, n * Fc + f, bf);
    Wbup[(((f >> 3) * 256) + col_re) * 8 + (f & 7)] = f2bf(cr * br - ci * bi);
    Wbup[(((f >> 3) * 256) + col_im) * 8 + (f & 7)] = f2bf(cr * bi + ci * br);
  }
}

// P2 packed bf16 [512/8][512][8]
__global__ __launch_bounds__(256) void k_P2p(const void* Df, const void* Db, const void* pw,
                                             const int* __restrict__ flag, u16* __restrict__ P2p) {
  int bf = *flag;
  int idx = blockIdx.x * 256 + threadIdx.x;
  int f1 = idx >> 9, fo = idx & 511;
  float v = ldf(Df, f1, bf) * ldf(pw, (long)f1 * Fc + fo, bf) +
            ldf(Db, f1, bf) * ldf(pw, (long)(Fc + f1) * Fc + fo, bf);
  P2p[(((f1 >> 3) * Fc) + fo) * 8 + (f1 & 7)] = f2bf(v);
}

// Cpm bf16 [256][512]: row k=dir*128+c*64+n, Cpm[k][f] = (+Cre|-Cim)[f][n]
__global__ __launch_bounds__(256) void k_Cpm(const void* Cref, const void* Cimf,
                                             const void* Creb, const void* Cimb,
                                             const int* __restrict__ flag, u16* __restrict__ Cpm) {
  int bf = *flag;
  int k = blockIdx.x;
  int dir = k >> 7, c = (k >> 6) & 1, n = k & 63;
  const void* C = dir ? (c ? Cimb : Creb) : (c ? Cimf : Cref);
  float sgn = c ? -1.f : 1.f;
  for (int f = threadIdx.x; f < Fc; f += 256)
    Cpm[k * Fc + f] = f2bf(sgn * ldf(C, (long)f * Nc + n, bf));
}

// generic raw [K,N] -> packed bf16 [K/8][N][8]; one thread per (k8,n)
__global__ __launch_bounds__(256) void k_Wpack(const void* __restrict__ src, const int* __restrict__ flag,
                                               int log2N, u16* __restrict__ dst) {
  int bf = *flag;
  long i = (long)blockIdx.x * 256 + threadIdx.x;     // over (K/8)*N
  int Nn = 1 << log2N;
  long k8 = i >> log2N;
  int n = (int)(i & (Nn - 1));
  u16 tmp[8];
#pragma unroll
  for (int j = 0; j < 8; ++j)
    tmp[j] = f2bf(ldf(src, ((k8 << 3) + j) * (long)Nn + n, bf));
  *(ushort4*)(dst + i * 8)     = *(ushort4*)tmp;
  *(ushort4*)(dst + i * 8 + 4) = *(ushort4*)(tmp + 4);
}

// ---------- LayerNorm + AdaLN ----------
__global__ __launch_bounds__(256) void k_ln(const void* __restrict__ src, int srcmode,
                                            long src_tok_base, int b0,
                                            const int* __restrict__ flag,
                                            const float* __restrict__ mods,
                                            int sh_base, int sc_base,
                                            u16* __restrict__ dst) {
  int bf = srcmode ? 1 : *flag;
  long lt = blockIdx.x;
  int b = b0 + (int)(lt >> 13);
  int t = threadIdx.x;
  long si = (src_tok_base + lt) * Fc;
  float x0 = ldf(src, si + t, bf);
  float x1 = ldf(src, si + t + 256, bf);
  float s = x0 + x1, qq = x0 * x0 + x1 * x1;
  for (int o = 32; o; o >>= 1) { s += __shfl_down(s, o); qq += __shfl_down(qq, o); }
  __shared__ float ss[4], sq[4];
  int w = t >> 6;
  if ((t & 63) == 0) { ss[w] = s; sq[w] = qq; }
  __syncthreads();
  float S = ss[0] + ss[1] + ss[2] + ss[3];
  float Q = sq[0] + sq[1] + sq[2] + sq[3];
  float mu = S * (1.f / Fc);
  float var = Q * (1.f / Fc) - mu * mu;
  float rs = rsqrtf(var + 1e-5f);
  const float* mb = mods + b * SIXF;
  float h0 = (x0 - mu) * rs * (1.f + mb[sc_base + t]) + mb[sh_base + t];
  float h1 = (x1 - mu) * rs * (1.f + mb[sc_base + t + 256]) + mb[sh_base + t + 256];
  dst[lt * Fc + t] = f2bf(h0);
  dst[lt * Fc + t + 256] = f2bf(h1);
}

// ---------- MFMA GEMM core: 2-phase pipelined, double-buffered LDS ----------
// A staged via global_load_lds with PRE-SWIZZLED global source (linear LDS dest,
// XOR-swizzled read). W staged linearly. 16B per lane per issue.
// Pipeline: stage(t+1) issued BEFORE compute(t); one vmcnt(0)+raw-barrier per
// iteration (NOT __syncthreads, which would drain vmcnt before the overlap).
// Buffer parity (cur) carries across passes: the pass-prologue barrier doubles
// as the previous pass's end barrier; staged buffer was last read 2 barriers ago.
struct Smem { u16 As[2][128 * 64]; u16 Ws[2][64 * 128]; };   // 64 KB

__device__ __forceinline__ int mfma_gemm(Smem& sm, int cur,
                                         const u16* __restrict__ A, long row0, int K,
                                         const u16* __restrict__ Wp, int N, int col0,
                                         f32x4 (&acc)[4][4]) {
  const int tid = threadIdx.x;
  const int l = tid & 63;
  const int q = l >> 4, li = l & 15;
  const int w = tid >> 6;
  const int wm = (w >> 1) << 6, wn = (w & 1) << 6;
  // per-thread loop-invariant source offsets (elements)
  const int m0 = tid >> 3;
  const int kc0 = (tid & 7) ^ (m0 & 7);            // invariant under c += 256 (m += 32)
  const long aoff0 = (row0 + m0) * (long)K + (kc0 << 3);
  const long woff0 = (long)(tid >> 7) * ((long)N << 3) + ((long)(col0 + (tid & 127)) << 3);
  const int lbase = w << 9;                        // wave-uniform LDS base (elements)
  const int T = K >> 6;

  auto stage = [&](int buf, int k0) {
#pragma unroll
    for (int it = 0; it < 4; ++it)
      ld16(A + aoff0 + (long)it * ((long)K << 5) + k0, sm.As[buf] + lbase + (it << 11));
#pragma unroll
    for (int it = 0; it < 4; ++it)
      ld16(Wp + woff0 + (long)k0 * N + (long)it * ((long)N << 4), sm.Ws[buf] + lbase + (it << 11));
  };

  // prologue: stage tile 0, wait, barrier
  stage(cur, 0);
  asm volatile("s_waitcnt vmcnt(0)" ::: "memory");
  __builtin_amdgcn_s_barrier();
  __builtin_amdgcn_sched_barrier(0);

  for (int t = 0; t < T; ++t) {
    if (t + 1 < T) stage(cur ^ 1, (t + 1) << 6);   // prefetch next tile (overlaps compute)
    const u16* As = sm.As[cur];
    const u16* Ws = sm.Ws[cur];
#pragma unroll
    for (int ks = 0; ks < 2; ++ks) {
      bf16x8 af[4], bw[4];
#pragma unroll
      for (int mt = 0; mt < 4; ++mt) {
        int mrow = wm + (mt << 4) + li;
        af[mt] = *(const bf16x8*)(As + (((mrow << 3) + (((ks << 2) + q) ^ (mrow & 7))) << 3));
      }
#pragma unroll
      for (int nt = 0; nt < 4; ++nt) {
        int n = wn + (nt << 4) + li;
        bw[nt] = *(const bf16x8*)(Ws + ((((((ks << 2) + q) << 7) + n)) << 3));
      }
#pragma unroll
      for (int mt = 0; mt < 4; ++mt)
#pragma unroll
        for (int nt = 0; nt < 4; ++nt)
          acc[mt][nt] = __builtin_amdgcn_mfma_f32_16x16x32_bf16(af[mt], bw[nt], acc[mt][nt], 0, 0, 0);
    }
    if (t + 1 < T) {
      asm volatile("s_waitcnt vmcnt(0)" ::: "memory");   // next tile's loads (mostly landed)
      __builtin_amdgcn_s_barrier();
      __builtin_amdgcn_sched_barrier(0);
    }
    cur ^= 1;
  }
  return cur;
}

// G via MFMA: Cpm[256,512] @ pwp(dir half) -> packed Gp
__global__ __launch_bounds__(256) void k_Gp2(const u16* __restrict__ Cpm, const u16* __restrict__ pwp,
                                             u16* __restrict__ Gp) {
  __shared__ Smem sm;
  f32x4 acc[4][4] = {};
  int bx, by; xcd_swz(bx, by);
  long row0 = (long)by * 128;
  int col0 = bx << 7;
  int dir = (int)(row0 >> 7);
  mfma_gemm(sm, 0, Cpm, row0, Fc, pwp + (size_t)dir * 262144, Fc, col0, acc);
  const int l = threadIdx.x & 63, q = l >> 4, li = l & 15;
  const int w = threadIdx.x >> 6;
  const int wm = (w >> 1) << 6, wn = (w & 1) << 6;
#pragma unroll
  for (int mt = 0; mt < 4; ++mt)
#pragma unroll
    for (int nt = 0; nt < 4; ++nt)
#pragma unroll
      for (int r = 0; r < 4; ++r) {
        int k = (int)row0 + wm + (mt << 4) + (q << 2) + r;
        int col = col0 + wn + (nt << 4) + li;
        Gp[(((k >> 3) * Fc) + col) * 8 + (k & 7)] = f2bf(acc[mt][nt][r]);
      }
}

// Bu GEMM: h[nb*8192,512] @ Wbu -> Bu[dir][lb][n][s][2] (bwd s flipped)
__global__ __launch_bounds__(256) void k_gemm_bu(const u16* __restrict__ h,
                                                 const u16* __restrict__ Wbup,
                                                 int nb, float* __restrict__ Bu) {
  __shared__ Smem sm;
  f32x4 acc[4][4] = {};
  int bx, by; xcd_swz(bx, by);
  long row0 = (long)by * 128;
  int col0 = bx << 7;
  mfma_gemm(sm, 0, h, row0, Fc, Wbup, 256, col0, acc);
  const int l = threadIdx.x & 63, q = l >> 4, li = l & 15;
  const int w = threadIdx.x >> 6;
  const int wm = (w >> 1) << 6, wn = (w & 1) << 6;
#pragma unroll
  for (int mt = 0; mt < 4; ++mt) {
#pragma unroll
    for (int nt = 0; nt < 4; ++nt) {
      int col = col0 + wn + (nt << 4) + li;
      int dir = col >> 7, cc = (col >> 6) & 1, n = col & 63;
#pragma unroll
      for (int r = 0; r < 4; ++r) {
        long lt = row0 + wm + (mt << 4) + (q << 2) + r;
        int lb = (int)(lt >> 13), s = (int)(lt & 8191);
        int spos = dir ? (Sc - 1 - s) : s;
        Bu[((((long)dir * nb + lb) * Nc + n) * Sc + spos) * 2 + cc] = acc[mt][nt][r];
      }
    }
  }
}

// chunked complex linear scan, in-place on Bu (float4 I/O). One block per (dir,lb,n).
__global__ __launch_bounds__(256) void k_scan(float* __restrict__ Bu, const float* __restrict__ Abar,
                                              int nb) {
  int blk = blockIdx.x;
  int per_dir = nb * 64;
  int dir = blk / per_dir;
  int rem = blk - dir * per_dir;
  int lb = rem >> 6, n = rem & 63;
  float ar = Abar[(dir * Nc + n) * 2 + 0];
  float ai = Abar[(dir * Nc + n) * 2 + 1];
  float* base = Bu + (((long)dir * nb + lb) * Nc + n) * Sc * 2;
  int t = threadIdx.x;
  float4 loc[16];
  float lr = 0.f, li = 0.f;
  const float4* bp = (const float4*)base + t * 16;
#pragma unroll
  for (int j = 0; j < 16; ++j) {
    float4 v = bp[j];
    loc[j] = v;
    float nr = fmaf(ar, lr, fmaf(-ai, li, v.x));
    float ni = fmaf(ar, li, fmaf(ai, lr, v.y));
    lr = fmaf(ar, nr, fmaf(-ai, ni, v.z));
    li = fmaf(ar, ni, fmaf(ai, nr, v.w));
  }
  __shared__ float sr[256], si[256];
  float pr = ar, pi = ai;
  for (int k = 0; k < 5; ++k) { float t2 = pr * pr - pi * pi; pi = 2.f * pr * pi; pr = t2; }  // a^32
  float vr = lr, vi = li;
  for (int step = 1; step < 256; step <<= 1) {
    sr[t] = vr; si[t] = vi;
    __syncthreads();
    if (t >= step) {
      float orr = sr[t - step], oii = si[t - step];
      vr = vr + pr * orr - pi * oii;
      vi = vi + pr * oii + pi * orr;
    }
    __syncthreads();
    float t2 = pr * pr - pi * pi; pi = 2.f * pr * pi; pr = t2;
  }
  sr[t] = vr; si[t] = vi;
  __syncthreads();
  float xr = (t == 0) ? 0.f : sr[t - 1];
  float xi = (t == 0) ? 0.f : si[t - 1];
  float4* op = (float4*)base + t * 16;
#pragma unroll
  for (int j = 0; j < 16; ++j) {
    float4 v = loc[j];
    float nr = fmaf(ar, xr, fmaf(-ai, xi, v.x));
    float ni = fmaf(ar, xi, fmaf(ai, xr, v.y));
    xr = fmaf(ar, nr, fmaf(-ai, ni, v.z));
    xi = fmaf(ar, ni, fmaf(ai, nr, v.w));
    float4 o; o.x = nr; o.y = ni; o.z = xr; o.w = xi;
    op[j] = o;
  }
}

// gather xs -> token-major bf16 hi/lo via LDS transpose (32 tokens x 256 cols per block)
__global__ __launch_bounds__(256) void k_xs_t(const float* __restrict__ xs, int nb,
                                              u16* __restrict__ xh, u16* __restrict__ xl) {
  __shared__ float tile[32 * 257];
  long t0 = (long)blockIdx.x * 32;
  int lb = (int)(t0 >> 13);
  int s0 = (int)(t0 & 8191);
  int tid = threadIdx.x;
  int ls = tid & 31;
  int half = (tid >> 5) & 1;      // two cols per wave-instruction
  int wv = tid >> 6;
#pragma unroll 4
  for (int cg = 0; cg < 32; ++cg) {
    int col = cg * 8 + wv * 2 + half;
    int dir = col >> 7, cc = (col >> 6) & 1, n = col & 63;
    int spos = dir ? (Sc - 1 - (s0 + ls)) : (s0 + ls);
    float v = xs[((((long)dir * nb + lb) * Nc + n) * Sc + spos) * 2 + cc];
    tile[ls * 257 + col] = v;
  }
  __syncthreads();
  for (int j = 0; j < 32; ++j) {
    float v = tile[j * 257 + tid];
    u16 hi = f2bf(v);
    long lt = t0 + j;
    xh[lt * 256 + tid] = hi;
    xl[lt * 256 + tid] = f2bf(v - bf2f(hi));
  }
}

// out1 = bf16( x + g1*(xs@G + h@P2 + pb) )
__global__ __launch_bounds__(256) void k_gemm_y(const u16* __restrict__ xh, const u16* __restrict__ xl,
                                                const u16* __restrict__ Gp,
                                                const u16* __restrict__ h, const u16* __restrict__ P2p,
                                                const void* __restrict__ xraw, long tok_base, int b0,
                                                const int* __restrict__ flag,
                                                const float* __restrict__ mods, const float* __restrict__ pb,
                                                u16* __restrict__ out1) {
  __shared__ Smem sm;
  f32x4 acc[4][4] = {};
  int bx, by; xcd_swz(bx, by);
  long row0 = (long)by * 128;
  int col0 = bx << 7;
  int cur = 0;
  cur = mfma_gemm(sm, cur, xh, row0, 256, Gp, Fc, col0, acc);
  cur = mfma_gemm(sm, cur, xl, row0, 256, Gp, Fc, col0, acc);
  cur = mfma_gemm(sm, cur, h, row0, Fc, P2p, Fc, col0, acc);
  int bf = *flag;
  const int l = threadIdx.x & 63, q = l >> 4, li = l & 15;
  const int w = threadIdx.x >> 6;
  const int wm = (w >> 1) << 6, wn = (w & 1) << 6;
#pragma unroll
  for (int mt = 0; mt < 4; ++mt) {
#pragma unroll
    for (int r = 0; r < 4; ++r) {
      long lt = row0 + wm + (mt << 4) + (q << 2) + r;
      int b = b0 + (int)(lt >> 13);
      const float* mb = mods + b * SIXF + 2 * Fc;
#pragma unroll
      for (int nt = 0; nt < 4; ++nt) {
        int col = col0 + wn + (nt << 4) + li;
        float xv = ldf(xraw, (tok_base + lt) * Fc + col, bf);
        out1[lt * Fc + col] = f2bf(xv + mb[col] * (acc[mt][nt][r] + pb[col]));
      }
    }
  }
}

// tanh-approx gelu via hardware exp2+rcp:
//   0.5*u*(1+tanh(z)) == u * sigmoid(2z);  sigmoid(2z) = 1/(1+exp(-2z))
__device__ __forceinline__ float gelu_t(float u) {
  float z = 0.7978845608028654f * fmaf(0.044715f * u * u, u, u);
  float e = __builtin_amdgcn_exp2f(z * -2.8853900817779268f);   // exp(-2z)
  return u * __builtin_amdgcn_rcpf(1.f + e);
}

__global__ __launch_bounds__(256) void k_mlp1(const u16* __restrict__ h2, const u16* __restrict__ W1p,
                                              const float* __restrict__ b1, long crow0,
                                              u16* __restrict__ tbuf) {
  __shared__ Smem sm;
  f32x4 acc[4][4] = {};
  int bx, by; xcd_swz(bx, by);
  long row0 = crow0 + (long)by * 128;
  int col0 = bx << 7;
  mfma_gemm(sm, 0, h2, row0, Fc, W1p, Hc, col0, acc);
  const int l = threadIdx.x & 63, q = l >> 4, li = l & 15;
  const int w = threadIdx.x >> 6;
  const int wm = (w >> 1) << 6, wn = (w & 1) << 6;
#pragma unroll
  for (int mt = 0; mt < 4; ++mt) {
#pragma unroll
    for (int r = 0; r < 4; ++r) {
      long lr2 = row0 - crow0 + wm + (mt << 4) + (q << 2) + r;
#pragma unroll
      for (int nt = 0; nt < 4; ++nt) {
        int col = col0 + wn + (nt << 4) + li;
        tbuf[lr2 * Hc + col] = f2bf(gelu_t(acc[mt][nt][r] + b1[col]));
      }
    }
  }
}

__global__ __launch_bounds__(256) void k_mlp2(const u16* __restrict__ tbuf, const u16* __restrict__ W2p,
                                              const float* __restrict__ b2, const u16* __restrict__ out1,
                                              const float* __restrict__ mods, long crow0,
                                              long tok_base, int b0,
                                              const int* __restrict__ flag, void* __restrict__ dout) {
  __shared__ Smem sm;
  f32x4 acc[4][4] = {};
  int bx, by; xcd_swz(bx, by);
  long lrow0 = (long)by * 128;
  int col0 = bx << 7;
  mfma_gemm(sm, 0, tbuf, lrow0, Hc, W2p, Fc, col0, acc);
  int bf = *flag;
  const int l = threadIdx.x & 63, q = l >> 4, li = l & 15;
  const int w = threadIdx.x >> 6;
  const int wm = (w >> 1) << 6, wn = (w & 1) << 6;
#pragma unroll
  for (int mt = 0; mt < 4; ++mt) {
#pragma unroll
    for (int r = 0; r < 4; ++r) {
      long lt = crow0 + lrow0 + wm + (mt << 4) + (q << 2) + r;
      int b = b0 + (int)(lt >> 13);
      const float* mb = mods + b * SIXF + 5 * Fc;
#pragma unroll
      for (int nt = 0; nt < 4; ++nt) {
        int col = col0 + wn + (nt << 4) + li;
        float v = bf2f(out1[lt * Fc + col]) + mb[col] * (acc[mt][nt][r] + b2[col]);
        long oi = (tok_base + lt) * Fc + col;
        if (bf) ((u16*)dout)[oi] = f2bf(v);
        else    ((float*)dout)[oi] = v;
      }
    }
  }
}

extern "C" void kernel_launch(void* const* d_in, const int* in_sizes, int n_in,
                              void* d_out, int out_size, void* d_ws, size_t ws_size,
                              hipStream_t stream) {
  char* ws = (char*)d_ws;
  size_t off = 0;
  auto alloc = [&](size_t bytes) -> char* {
    char* p = ws + off;
    off += (bytes + 255) & ~(size_t)255;
    return p;
  };
  int*   flag = (int*)  alloc(4);
  float* mods = (float*)alloc((size_t)Bc * SIXF * 4);
  float* Abar = (float*)alloc(2 * Nc * 2 * 4);
  float* pbf  = (float*)alloc(Fc * 4);
  float* b1f  = (float*)alloc(Hc * 4);
  float* b2f  = (float*)alloc(Fc * 4);
  u16* Wbup = (u16*)alloc((size_t)Fc * 256 * 2);
  u16* Gp   = (u16*)alloc((size_t)256 * Fc * 2);
  u16* P2p  = (u16*)alloc((size_t)Fc * Fc * 2);
  u16* W1p  = (u16*)alloc((size_t)Fc * Hc * 2);
  u16* W2p  = (u16*)alloc((size_t)Hc * Fc * 2);
  u16* pwp  = (u16*)alloc((size_t)1024 * Fc * 2);
  u16* Cpm  = (u16*)alloc((size_t)256 * Fc * 2);
  size_t off_static = off;

  const size_t U = (size_t)Sc * Fc * 2;   // 8.39 MB per batch unit
  int nb = 4;
  while (nb > 1 && off_static + (size_t)nb * 4 * U + 4096 > ws_size) nb >>= 1;

  u16*   h    = (u16*)  alloc((size_t)nb * U);
  float* Bu   = (float*)alloc((size_t)nb * U);
  u16*   xh   = (u16*)  alloc((size_t)nb * U / 2);
  u16*   xl   = (u16*)  alloc((size_t)nb * U / 2);
  u16*   out1 = (u16*)  alloc((size_t)nb * U);
  // MLP phase overlays (all producers of these regions are dead by then):
  //   h2   -> h region   (h dead after k_gemm_y)
  //   tbuf -> Bu+xh+xl   (2*nb*U bytes contiguous; Bu/xh/xl dead after k_gemm_y)
  // tbuf holds one half-row chunk: (rows/2)*Hc*2 = nb*U*2 bytes exactly.
  u16* tch = (u16*)Bu;
  u16* h2  = h;

  // detection + scalar conversions
  k_detect<<<1, 64, 0, stream>>>((const u16*)d_in[0], flag);
  k_convert<<<2, 256, 0, stream>>>(d_in[19], pbf, Fc, flag);
  k_convert<<<8, 256, 0, stream>>>(d_in[23], b1f, Hc, flag);
  k_convert<<<2, 256, 0, stream>>>(d_in[25], b2f, Fc, flag);
  // mods
  k_mods_init<<<12, 256, 0, stream>>>(d_in[21], flag, mods);
  k_mods2<<<dim3(12, Bc, 4), 256, 0, stream>>>(d_in[1], d_in[20], flag, mods);
  // S5 weights
  k_prep<<<dim3(2, 8), 64, 0, stream>>>(d_in[2], d_in[3], d_in[4], d_in[5], d_in[9],
                                        d_in[10], d_in[11], d_in[12], d_in[13], d_in[17],
                                        flag, Wbup, Abar);
  k_P2p<<<(Fc * Fc) / 256, 256, 0, stream>>>(d_in[8], d_in[16], d_in[18], flag, P2p);
  // G via MFMA: pack proj_w (1024x512) + build Cpm, then GEMM
  k_Wpack<<<256, 256, 0, stream>>>(d_in[18], flag, 9, pwp);
  k_Cpm<<<256, 256, 0, stream>>>(d_in[6], d_in[7], d_in[14], d_in[15], flag, Cpm);
  k_Gp2<<<dim3(4, 2), 256, 0, stream>>>(Cpm, pwp, Gp);
  // MLP weights
  k_Wpack<<<512, 256, 0, stream>>>(d_in[22], flag, 11, W1p);
  k_Wpack<<<512, 256, 0, stream>>>(d_in[24], flag, 9, W2p);

  for (int b0 = 0; b0 < Bc; b0 += nb) {
    long tok_base = (long)b0 * Sc;
    long rows = (long)nb * Sc;
    k_ln<<<rows, 256, 0, stream>>>(d_in[0], 0, tok_base, b0, flag, mods, 0, Fc, h);
    k_gemm_bu<<<dim3(2, rows / 128), 256, 0, stream>>>(h, Wbup, nb, Bu);
    k_scan<<<2 * nb * 64, 256, 0, stream>>>(Bu, Abar, nb);
    k_xs_t<<<rows / 32, 256, 0, stream>>>(Bu, nb, xh, xl);
    k_gemm_y<<<dim3(Fc / 128, rows / 128), 256, 0, stream>>>(xh, xl, Gp, h, P2p,
                                                             d_in[0], tok_base, b0, flag, mods, pbf, out1);
    k_ln<<<rows, 256, 0, stream>>>(out1, 1, 0, b0, flag, mods, 3 * Fc, 4 * Fc, h2);
    long RC = rows / 2;                  // 2 chunks: doubles mlp grids vs 4-chunk version
    for (int ch = 0; ch < 2; ++ch) {
      long crow0 = ch * RC;
      k_mlp1<<<dim3(Hc / 128, RC / 128), 256, 0, stream>>>(h2, W1p, b1f, crow0, tch);
      k_mlp2<<<dim3(Fc / 128, RC / 128), 256, 0, stream>>>(tch, W2p, b2f, out1, mods, crow0,
                                                           tok_base, b0, flag, d_out);
    }
  }
  (void)n_in; (void)out_size; (void)in_sizes;
}

// Round 5
// 623.523 us; speedup vs baseline: 1.3378x; 1.0256x over previous
//
#include <hip/hip_runtime.h>
#include <hip/hip_bf16.h>

typedef unsigned short u16;
typedef __attribute__((ext_vector_type(8))) short bf16x8;
typedef __attribute__((ext_vector_type(4))) float f32x4;

#define Bc 4
#define Sc 8192
#define Fc 512
#define Nc 64
#define Hc 2048
#define SIXF 3072

__device__ __forceinline__ u16 f2bf(float v) {
  __hip_bfloat16 h = __float2bfloat16(v);
  return *reinterpret_cast<u16*>(&h);
}
__device__ __forceinline__ float bf2f(u16 u) {
  return __uint_as_float(((unsigned)u) << 16);
}
__device__ __forceinline__ float ldf(const void* p, long i, int bf) {
  return bf ? bf2f(((const u16*)p)[i]) : ((const float*)p)[i];
}

// async global->LDS, 16 bytes per lane. LDS dest is wave-uniform base + lane*16.
__device__ __forceinline__ void ld16(const u16* g, u16* l) {
  __builtin_amdgcn_global_load_lds(
      (const __attribute__((address_space(1))) unsigned int*)g,
      (__attribute__((address_space(3))) unsigned int*)l,
      16, 0, 0);
}

// XCD-aware bijective block remap (valid when nwg % 8 == 0; identity otherwise).
__device__ __forceinline__ void xcd_swz(int& bx, int& by) {
  int gx = gridDim.x;
  int nwg = gx * gridDim.y;
  int lin = blockIdx.x + gx * blockIdx.y;
  if ((nwg & 7) == 0) {
    int q = nwg >> 3;
    lin = (lin & 7) * q + (lin >> 3);
  }
  bx = lin % gx;
  by = lin / gx;
}

// ---------- dtype detection ----------
__global__ void k_detect(const u16* __restrict__ x, int* __restrict__ flag) {
  if (threadIdx.x == 0) {
    int cnt = 0;
    for (int i = 0; i < 256; ++i) {
      int e = (x[i] >> 7) & 0xFF;
      cnt += (e >= 130);
    }
    *flag = (cnt >= 16) ? 0 : 1;   // 1 = bf16 inputs, 0 = fp32
  }
}

__global__ void k_convert(const void* __restrict__ src, float* __restrict__ dst,
                          int n, const int* __restrict__ flag) {
  int bf = *flag;
  int i = blockIdx.x * blockDim.x + threadIdx.x;
  int stride = gridDim.x * blockDim.x;
  for (int j = i; j < n; j += stride) dst[j] = ldf(src, j, bf);
}

// ---------- mods ----------
__global__ __launch_bounds__(256) void k_mods_init(const void* __restrict__ ada_b,
                                                   const int* __restrict__ flag,
                                                   float* __restrict__ mods) {
  int bf = *flag;
  int col = blockIdx.x * 256 + threadIdx.x;   // grid 12
  float v = ldf(ada_b, col, bf);
  for (int b = 0; b < Bc; ++b) mods[b * SIXF + col] = v;
}

__global__ __launch_bounds__(256) void k_mods2(const void* __restrict__ cond,
                                               const void* __restrict__ ada_w,
                                               const int* __restrict__ flag,
                                               float* __restrict__ mods) {
  int bf = *flag;
  int b = blockIdx.y;
  int f0 = blockIdx.z * 128;
  int col = blockIdx.x * 256 + threadIdx.x;
  __shared__ float sc[128];
  for (int i = threadIdx.x; i < 128; i += 256) {
    float c = ldf(cond, b * Fc + f0 + i, bf);
    sc[i] = c / (1.f + expf(-c));
  }
  __syncthreads();
  float acc = 0.f;
  for (int f = 0; f < 128; ++f) acc = fmaf(sc[f], ldf(ada_w, (long)(f0 + f) * SIXF + col, bf), acc);
  atomicAdd(&mods[b * SIXF + col], acc);
}

// ---------- Abar + Wbu packed ----------
__global__ void k_prep(const void* lAf, const void* Aif, const void* Brf, const void* Bif, const void* ldtf,
                       const void* lAb, const void* Aib, const void* Brb, const void* Bib, const void* ldtb,
                       const int* __restrict__ flag,
                       u16* __restrict__ Wbup, float* __restrict__ Abar) {
  int bf = *flag;
  int dir = blockIdx.x;
  int f0 = blockIdx.y * 64;     // grid (2, 8)
  int n = threadIdx.x;          // 64
  const void* lA = dir ? lAb : lAf;
  const void* Ai = dir ? Aib : Aif;
  const void* Br = dir ? Brb : Brf;
  const void* Bi = dir ? Bib : Bif;
  const void* ld = dir ? ldtb : ldtf;
  float dt  = expf(ldf(ld, n, bf));
  float Are = -expf(ldf(lA, n, bf));
  float Aim = ldf(Ai, n, bf);
  float er  = expf(Are * dt);
  float abr = er * cosf(Aim * dt);
  float abi = er * sinf(Aim * dt);
  if (blockIdx.y == 0) {
    Abar[(dir * Nc + n) * 2 + 0] = abr;
    Abar[(dir * Nc + n) * 2 + 1] = abi;
  }
  float dr = Are + 1e-8f, di = Aim;
  float den = dr * dr + di * di;
  float nr = abr - 1.f, ni = abi;
  float cr = (nr * dr + ni * di) / den;
  float ci = (ni * dr - nr * di) / den;
  int col_re = dir * 128 + n, col_im = dir * 128 + 64 + n;
  for (int f = f0; f < f0 + 64; ++f) {
    float br = ldf(Br, n * Fc + f, bf), bi = ldf(Bi, n * Fc + f, bf);
    Wbup[(((f >> 3) * 256) + col_re) * 8 + (f & 7)] = f2bf(cr * br - ci * bi);
    Wbup[(((f >> 3) * 256) + col_im) * 8 + (f & 7)] = f2bf(cr * bi + ci * br);
  }
}

// P2 -> Wyp rows 512..1023 (packed [K/8][512][8], K=1024)
__global__ __launch_bounds__(256) void k_P2p(const void* Df, const void* Db, const void* pw,
                                             const int* __restrict__ flag, u16* __restrict__ Wyp) {
  int bf = *flag;
  int idx = blockIdx.x * 256 + threadIdx.x;
  int f1 = idx >> 9, fo = idx & 511;
  float v = ldf(Df, f1, bf) * ldf(pw, (long)f1 * Fc + fo, bf) +
            ldf(Db, f1, bf) * ldf(pw, (long)(Fc + f1) * Fc + fo, bf);
  Wyp[((((f1 >> 3) + 64) * Fc) + fo) * 8 + (f1 & 7)] = f2bf(v);
}

// Cpm bf16 [256][512]
__global__ __launch_bounds__(256) void k_Cpm(const void* Cref, const void* Cimf,
                                             const void* Creb, const void* Cimb,
                                             const int* __restrict__ flag, u16* __restrict__ Cpm) {
  int bf = *flag;
  int k = blockIdx.x;
  int dir = k >> 7, c = (k >> 6) & 1, n = k & 63;
  const void* C = dir ? (c ? Cimb : Creb) : (c ? Cimf : Cref);
  float sgn = c ? -1.f : 1.f;
  for (int f = threadIdx.x; f < Fc; f += 256)
    Cpm[k * Fc + f] = f2bf(sgn * ldf(C, (long)f * Nc + n, bf));
}

// generic raw [K,N] -> packed bf16 [K/8][N][8]
__global__ __launch_bounds__(256) void k_Wpack(const void* __restrict__ src, const int* __restrict__ flag,
                                               int log2N, u16* __restrict__ dst) {
  int bf = *flag;
  long i = (long)blockIdx.x * 256 + threadIdx.x;
  int Nn = 1 << log2N;
  long k8 = i >> log2N;
  int n = (int)(i & (Nn - 1));
  u16 tmp[8];
#pragma unroll
  for (int j = 0; j < 8; ++j)
    tmp[j] = f2bf(ldf(src, ((k8 << 3) + j) * (long)Nn + n, bf));
  *(ushort4*)(dst + i * 8)     = *(ushort4*)tmp;
  *(ushort4*)(dst + i * 8 + 4) = *(ushort4*)(tmp + 4);
}

// ---------- LayerNorm + AdaLN (dest stride/offset params for hxl fusion) ----------
__global__ __launch_bounds__(256) void k_ln(const void* __restrict__ src, int srcmode,
                                            long src_tok_base, int b0,
                                            const int* __restrict__ flag,
                                            const float* __restrict__ mods,
                                            int sh_base, int sc_base,
                                            u16* __restrict__ dst, int ldd, int dcol) {
  int bf = srcmode ? 1 : *flag;
  long lt = blockIdx.x;
  int b = b0 + (int)(lt >> 13);
  int t = threadIdx.x;
  long si = (src_tok_base + lt) * Fc;
  float x0 = ldf(src, si + t, bf);
  float x1 = ldf(src, si + t + 256, bf);
  float s = x0 + x1, qq = x0 * x0 + x1 * x1;
  for (int o = 32; o; o >>= 1) { s += __shfl_down(s, o); qq += __shfl_down(qq, o); }
  __shared__ float ss[4], sq[4];
  int w = t >> 6;
  if ((t & 63) == 0) { ss[w] = s; sq[w] = qq; }
  __syncthreads();
  float S = ss[0] + ss[1] + ss[2] + ss[3];
  float Q = sq[0] + sq[1] + sq[2] + sq[3];
  float mu = S * (1.f / Fc);
  float var = Q * (1.f / Fc) - mu * mu;
  float rs = rsqrtf(var + 1e-5f);
  const float* mb = mods + b * SIXF;
  float h0 = (x0 - mu) * rs * (1.f + mb[sc_base + t]) + mb[sh_base + t];
  float h1 = (x1 - mu) * rs * (1.f + mb[sc_base + t + 256]) + mb[sh_base + t + 256];
  dst[lt * (long)ldd + dcol + t] = f2bf(h0);
  dst[lt * (long)ldd + dcol + t + 256] = f2bf(h1);
}

// ---------- 128x128 MFMA core (256 thr): 2-barrier counted-vmcnt pipeline ----------
// A via global_load_lds, pre-swizzled source (linear LDS dest, XOR-swizzled read).
// stage(t+1) -> vmcnt(8) [t's 8 loads done, t+1's stay in flight] -> barrier ->
// MFMA(t) -> barrier [WAR guard before buffer reuse].
struct SmemA { u16 As[2][128 * 64]; u16 Ws[2][64 * 128]; };   // 64 KB

__device__ __forceinline__ void mfma_gemm128(SmemA& sm, const u16* __restrict__ A, long row0,
                                             int lda, int K,
                                             const u16* __restrict__ Wp, int N, int col0,
                                             f32x4 (&acc)[4][4]) {
  const int tid = threadIdx.x;
  const int l = tid & 63, q = l >> 4, li = l & 15;
  const int w = tid >> 6;
  const int wm = (w >> 1) << 6, wn = (w & 1) << 6;
  const int m0 = tid >> 3;                          // 0..31
  const int kc0 = (tid & 7) ^ (m0 & 7);             // invariant under m0+32
  const long aoff0 = (row0 + m0) * (long)lda + (kc0 << 3);
  const long woff0 = (long)(tid >> 7) * ((long)N << 3) + ((long)(col0 + (tid & 127)) << 3);
  const int lb = w << 9;
  const int T = K >> 6;
  int cur = 0;
  auto stage = [&](int buf, int k0) {
#pragma unroll
    for (int it = 0; it < 4; ++it)
      ld16(A + aoff0 + (long)it * ((long)lda << 5) + k0, sm.As[buf] + (it << 11) + lb);
#pragma unroll
    for (int it = 0; it < 4; ++it)
      ld16(Wp + woff0 + (long)k0 * N + (long)it * ((long)N << 4), sm.Ws[buf] + (it << 11) + lb);
  };
  stage(0, 0);
  for (int t = 0; t < T; ++t) {
    if (t + 1 < T) {
      stage(cur ^ 1, (t + 1) << 6);
      asm volatile("s_waitcnt vmcnt(8)" ::: "memory");
    } else {
      asm volatile("s_waitcnt vmcnt(0)" ::: "memory");
    }
    __builtin_amdgcn_s_barrier();
    __builtin_amdgcn_sched_barrier(0);
    const u16* As = sm.As[cur];
    const u16* Ws = sm.Ws[cur];
#pragma unroll
    for (int ks = 0; ks < 2; ++ks) {
      bf16x8 af[4], bw[4];
#pragma unroll
      for (int mt = 0; mt < 4; ++mt) {
        int mrow = wm + (mt << 4) + li;
        af[mt] = *(const bf16x8*)(As + (((mrow << 3) + (((ks << 2) + q) ^ (mrow & 7))) << 3));
      }
#pragma unroll
      for (int nt = 0; nt < 4; ++nt) {
        int n = wn + (nt << 4) + li;
        bw[nt] = *(const bf16x8*)(Ws + (((((ks << 2) + q) << 7) | n) << 3));
      }
#pragma unroll
      for (int mt = 0; mt < 4; ++mt)
#pragma unroll
        for (int nt = 0; nt < 4; ++nt)
          acc[mt][nt] = __builtin_amdgcn_mfma_f32_16x16x32_bf16(af[mt], bw[nt], acc[mt][nt], 0, 0, 0);
    }
    __builtin_amdgcn_s_barrier();
    __builtin_amdgcn_sched_barrier(0);
    cur ^= 1;
  }
}

// ---------- 256x256 MFMA core (512 thr, 8 waves 2x4): same schedule, 2x intensity ----------
struct SmemB { u16 As[2][256 * 64]; u16 Ws[2][64 * 256]; };   // 128 KB

__device__ __forceinline__ void mfma_gemm256(SmemB& sm, const u16* __restrict__ A, long row0,
                                             int lda, int K,
                                             const u16* __restrict__ Wp, int N, int col0,
                                             f32x4 (&acc)[8][4]) {
  const int tid = threadIdx.x;
  const int l = tid & 63, q = l >> 4, li = l & 15;
  const int w = tid >> 6;
  const int wm = (w >> 2) << 7, wn = (w & 3) << 6;
  const int m0 = tid >> 3;                          // 0..63
  const int kc0 = (tid & 7) ^ (m0 & 7);             // invariant under m0+64
  const long aoff0 = (row0 + m0) * (long)lda + (kc0 << 3);
  const long woff0 = (long)(tid >> 8) * ((long)N << 3) + ((long)(col0 + (tid & 255)) << 3);
  const int lb = w << 9;
  const int T = K >> 6;
  int cur = 0;
  auto stage = [&](int buf, int k0) {
#pragma unroll
    for (int it = 0; it < 4; ++it)
      ld16(A + aoff0 + (long)it * ((long)lda << 6) + k0, sm.As[buf] + (it << 12) + lb);
#pragma unroll
    for (int it = 0; it < 4; ++it)
      ld16(Wp + woff0 + (long)k0 * N + (long)it * ((long)N << 4), sm.Ws[buf] + (it << 12) + lb);
  };
  stage(0, 0);
  for (int t = 0; t < T; ++t) {
    if (t + 1 < T) {
      stage(cur ^ 1, (t + 1) << 6);
      asm volatile("s_waitcnt vmcnt(8)" ::: "memory");
    } else {
      asm volatile("s_waitcnt vmcnt(0)" ::: "memory");
    }
    __builtin_amdgcn_s_barrier();
    __builtin_amdgcn_sched_barrier(0);
    const u16* As = sm.As[cur];
    const u16* Ws = sm.Ws[cur];
    __builtin_amdgcn_s_setprio(1);
#pragma unroll
    for (int ks = 0; ks < 2; ++ks) {
      bf16x8 bw[4];
#pragma unroll
      for (int nt = 0; nt < 4; ++nt) {
        int n = wn + (nt << 4) + li;
        bw[nt] = *(const bf16x8*)(Ws + (((((ks << 2) + q) << 8) | n) << 3));
      }
#pragma unroll
      for (int mt = 0; mt < 8; ++mt) {
        int mrow = wm + (mt << 4) + li;
        bf16x8 af = *(const bf16x8*)(As + (((mrow << 3) + (((ks << 2) + q) ^ (mrow & 7))) << 3));
#pragma unroll
        for (int nt = 0; nt < 4; ++nt)
          acc[mt][nt] = __builtin_amdgcn_mfma_f32_16x16x32_bf16(af, bw[nt], acc[mt][nt], 0, 0, 0);
      }
    }
    __builtin_amdgcn_s_setprio(0);
    __builtin_amdgcn_s_barrier();
    __builtin_amdgcn_sched_barrier(0);
    cur ^= 1;
  }
}

// G via MFMA: Cpm[256,512] @ pwp(dir half) -> Wyp rows 0..255 AND dup rows 256..511
__global__ __launch_bounds__(256) void k_Gp2(const u16* __restrict__ Cpm, const u16* __restrict__ pwp,
                                             u16* __restrict__ Wyp) {
  __shared__ SmemA sm;
  f32x4 acc[4][4] = {};
  int bx, by; xcd_swz(bx, by);
  long row0 = (long)by * 128;
  int col0 = bx << 7;
  int dir = (int)(row0 >> 7);
  mfma_gemm128(sm, Cpm, row0, Fc, Fc, pwp + (size_t)dir * 262144, Fc, col0, acc);
  const int l = threadIdx.x & 63, q = l >> 4, li = l & 15;
  const int w = threadIdx.x >> 6;
  const int wm = (w >> 1) << 6, wn = (w & 1) << 6;
#pragma unroll
  for (int mt = 0; mt < 4; ++mt)
#pragma unroll
    for (int nt = 0; nt < 4; ++nt)
#pragma unroll
      for (int r = 0; r < 4; ++r) {
        int k = (int)row0 + wm + (mt << 4) + (q << 2) + r;
        int col = col0 + wn + (nt << 4) + li;
        u16 v = f2bf(acc[mt][nt][r]);
        size_t i0 = (((size_t)(k >> 3)) * Fc + col) * 8 + (k & 7);
        Wyp[i0] = v;
        Wyp[i0 + (size_t)32 * Fc * 8] = v;   // duplicate for xl half
      }
}

// Bu GEMM: h (hxl cols 512..1023) @ Wbu -> Bu[dir][lb][n][s][2]
__global__ __launch_bounds__(256) void k_gemm_bu(const u16* __restrict__ hp,
                                                 const u16* __restrict__ Wbup,
                                                 int nb, float* __restrict__ Bu) {
  __shared__ SmemA sm;
  f32x4 acc[4][4] = {};
  int bx, by; xcd_swz(bx, by);
  long row0 = (long)by * 128;
  int col0 = bx << 7;
  mfma_gemm128(sm, hp, row0, 1024, Fc, Wbup, 256, col0, acc);
  const int l = threadIdx.x & 63, q = l >> 4, li = l & 15;
  const int w = threadIdx.x >> 6;
  const int wm = (w >> 1) << 6, wn = (w & 1) << 6;
#pragma unroll
  for (int mt = 0; mt < 4; ++mt) {
#pragma unroll
    for (int nt = 0; nt < 4; ++nt) {
      int col = col0 + wn + (nt << 4) + li;
      int dir = col >> 7, cc = (col >> 6) & 1, n = col & 63;
#pragma unroll
      for (int r = 0; r < 4; ++r) {
        long lt = row0 + wm + (mt << 4) + (q << 2) + r;
        int lb = (int)(lt >> 13), s = (int)(lt & 8191);
        int spos = dir ? (Sc - 1 - s) : s;
        Bu[((((long)dir * nb + lb) * Nc + n) * Sc + spos) * 2 + cc] = acc[mt][nt][r];
      }
    }
  }
}

// chunked complex linear scan, in-place on Bu
__global__ __launch_bounds__(256) void k_scan(float* __restrict__ Bu, const float* __restrict__ Abar,
                                              int nb) {
  int blk = blockIdx.x;
  int per_dir = nb * 64;
  int dir = blk / per_dir;
  int rem = blk - dir * per_dir;
  int lb = rem >> 6, n = rem & 63;
  float ar = Abar[(dir * Nc + n) * 2 + 0];
  float ai = Abar[(dir * Nc + n) * 2 + 1];
  float* base = Bu + (((long)dir * nb + lb) * Nc + n) * Sc * 2;
  int t = threadIdx.x;
  float4 loc[16];
  float lr = 0.f, li = 0.f;
  const float4* bp = (const float4*)base + t * 16;
#pragma unroll
  for (int j = 0; j < 16; ++j) {
    float4 v = bp[j];
    loc[j] = v;
    float nr = fmaf(ar, lr, fmaf(-ai, li, v.x));
    float ni = fmaf(ar, li, fmaf(ai, lr, v.y));
    lr = fmaf(ar, nr, fmaf(-ai, ni, v.z));
    li = fmaf(ar, ni, fmaf(ai, nr, v.w));
  }
  __shared__ float sr[256], si[256];
  float pr = ar, pi = ai;
  for (int k = 0; k < 5; ++k) { float t2 = pr * pr - pi * pi; pi = 2.f * pr * pi; pr = t2; }  // a^32
  float vr = lr, vi = li;
  for (int step = 1; step < 256; step <<= 1) {
    sr[t] = vr; si[t] = vi;
    __syncthreads();
    if (t >= step) {
      float orr = sr[t - step], oii = si[t - step];
      vr = vr + pr * orr - pi * oii;
      vi = vi + pr * oii + pi * orr;
    }
    __syncthreads();
    float t2 = pr * pr - pi * pi; pi = 2.f * pr * pi; pr = t2;
  }
  sr[t] = vr; si[t] = vi;
  __syncthreads();
  float xr = (t == 0) ? 0.f : sr[t - 1];
  float xi = (t == 0) ? 0.f : si[t - 1];
  float4* op = (float4*)base + t * 16;
#pragma unroll
  for (int j = 0; j < 16; ++j) {
    float4 v = loc[j];
    float nr = fmaf(ar, xr, fmaf(-ai, xi, v.x));
    float ni = fmaf(ar, xi, fmaf(ai, xr, v.y));
    xr = fmaf(ar, nr, fmaf(-ai, ni, v.z));
    xi = fmaf(ar, ni, fmaf(ai, nr, v.w));
    float4 o; o.x = nr; o.y = ni; o.z = xr; o.w = xi;
    op[j] = o;
  }
}

// gather xs -> token-major bf16 hi/lo into hxl cols [0..255]=hi, [256..511]=lo
__global__ __launch_bounds__(256) void k_xs_t(const float* __restrict__ xs, int nb,
                                              u16* __restrict__ hxl) {
  __shared__ float tile[32 * 257];
  long t0 = (long)blockIdx.x * 32;
  int lb = (int)(t0 >> 13);
  int s0 = (int)(t0 & 8191);
  int tid = threadIdx.x;
  int ls = tid & 31;
  int half = (tid >> 5) & 1;
  int wv = tid >> 6;
#pragma unroll 4
  for (int cg = 0; cg < 32; ++cg) {
    int col = cg * 8 + wv * 2 + half;
    int dir = col >> 7, cc = (col >> 6) & 1, n = col & 63;
    int spos = dir ? (Sc - 1 - (s0 + ls)) : (s0 + ls);
    float v = xs[((((long)dir * nb + lb) * Nc + n) * Sc + spos) * 2 + cc];
    tile[ls * 257 + col] = v;
  }
  __syncthreads();
  for (int j = 0; j < 32; ++j) {
    float v = tile[j * 257 + tid];
    u16 hi = f2bf(v);
    long lt = t0 + j;
    hxl[lt * 1024 + tid] = hi;
    hxl[lt * 1024 + 256 + tid] = f2bf(v - bf2f(hi));
  }
}

// out1 = bf16( x + g1*([xh|xl|h] @ [Gp;Gp;P2p] + pb) )   -- single fused K=1024 pass
__global__ __launch_bounds__(512, 2) void k_gemm_y(const u16* __restrict__ hxl,
                                                   const u16* __restrict__ Wyp,
                                                   const void* __restrict__ xraw, long tok_base, int b0,
                                                   const int* __restrict__ flag,
                                                   const float* __restrict__ mods,
                                                   const float* __restrict__ pb,
                                                   u16* __restrict__ out1) {
  __shared__ SmemB sm;
  f32x4 acc[8][4] = {};
  int bx, by; xcd_swz(bx, by);
  long row0 = (long)by << 8;
  int col0 = bx << 8;
  mfma_gemm256(sm, hxl, row0, 1024, 1024, Wyp, Fc, col0, acc);
  int bf = *flag;
  const int l = threadIdx.x & 63, q = l >> 4, li = l & 15;
  const int w = threadIdx.x >> 6;
  const int wm = (w >> 2) << 7, wn = (w & 3) << 6;
#pragma unroll
  for (int mt = 0; mt < 8; ++mt) {
#pragma unroll
    for (int r = 0; r < 4; ++r) {
      long lt = row0 + wm + (mt << 4) + (q << 2) + r;
      int b = b0 + (int)(lt >> 13);
      const float* mb = mods + b * SIXF + 2 * Fc;
#pragma unroll
      for (int nt = 0; nt < 4; ++nt) {
        int col = col0 + wn + (nt << 4) + li;
        float xv = ldf(xraw, (tok_base + lt) * Fc + col, bf);
        out1[lt * Fc + col] = f2bf(xv + mb[col] * (acc[mt][nt][r] + pb[col]));
      }
    }
  }
}

// tanh-approx gelu via hardware exp2+rcp
__device__ __forceinline__ float gelu_t(float u) {
  float z = 0.7978845608028654f * fmaf(0.044715f * u * u, u, u);
  float e = __builtin_amdgcn_exp2f(z * -2.8853900817779268f);   // exp(-2z)
  return u * __builtin_amdgcn_rcpf(1.f + e);
}

__global__ __launch_bounds__(512, 2) void k_mlp1(const u16* __restrict__ h2, const u16* __restrict__ W1p,
                                                 const float* __restrict__ b1, long crow0,
                                                 u16* __restrict__ tbuf) {
  __shared__ SmemB sm;
  f32x4 acc[8][4] = {};
  int bx, by; xcd_swz(bx, by);
  long row0 = crow0 + ((long)by << 8);
  int col0 = bx << 8;
  mfma_gemm256(sm, h2, row0, Fc, Fc, W1p, Hc, col0, acc);
  const int l = threadIdx.x & 63, q = l >> 4, li = l & 15;
  const int w = threadIdx.x >> 6;
  const int wm = (w >> 2) << 7, wn = (w & 3) << 6;
#pragma unroll
  for (int mt = 0; mt < 8; ++mt) {
#pragma unroll
    for (int r = 0; r < 4; ++r) {
      long lr2 = row0 - crow0 + wm + (mt << 4) + (q << 2) + r;
#pragma unroll
      for (int nt = 0; nt < 4; ++nt) {
        int col = col0 + wn + (nt << 4) + li;
        tbuf[lr2 * Hc + col] = f2bf(gelu_t(acc[mt][nt][r] + b1[col]));
      }
    }
  }
}

__global__ __launch_bounds__(256) void k_mlp2(const u16* __restrict__ tbuf, const u16* __restrict__ W2p,
                                              const float* __restrict__ b2, const u16* __restrict__ out1,
                                              const float* __restrict__ mods, long crow0,
                                              long tok_base, int b0,
                                              const int* __restrict__ flag, void* __restrict__ dout) {
  __shared__ SmemA sm;
  f32x4 acc[4][4] = {};
  int bx, by; xcd_swz(bx, by);
  long lrow0 = (long)by * 128;
  int col0 = bx << 7;
  mfma_gemm128(sm, tbuf, lrow0, Hc, Hc, W2p, Fc, col0, acc);
  int bf = *flag;
  const int l = threadIdx.x & 63, q = l >> 4, li = l & 15;
  const int w = threadIdx.x >> 6;
  const int wm = (w >> 1) << 6, wn = (w & 1) << 6;
#pragma unroll
  for (int mt = 0; mt < 4; ++mt) {
#pragma unroll
    for (int r = 0; r < 4; ++r) {
      long lt = crow0 + lrow0 + wm + (mt << 4) + (q << 2) + r;
      int b = b0 + (int)(lt >> 13);
      const float* mb = mods + b * SIXF + 5 * Fc;
#pragma unroll
      for (int nt = 0; nt < 4; ++nt) {
        int col = col0 + wn + (nt << 4) + li;
        float v = bf2f(out1[lt * Fc + col]) + mb[col] * (acc[mt][nt][r] + b2[col]);
        long oi = (tok_base + lt) * Fc + col;
        if (bf) ((u16*)dout)[oi] = f2bf(v);
        else    ((float*)dout)[oi] = v;
      }
    }
  }
}

extern "C" void kernel_launch(void* const* d_in, const int* in_sizes, int n_in,
                              void* d_out, int out_size, void* d_ws, size_t ws_size,
                              hipStream_t stream) {
  char* ws = (char*)d_ws;
  size_t off = 0;
  auto alloc = [&](size_t bytes) -> char* {
    char* p = ws + off;
    off += (bytes + 255) & ~(size_t)255;
    return p;
  };
  int*   flag = (int*)  alloc(4);
  float* mods = (float*)alloc((size_t)Bc * SIXF * 4);
  float* Abar = (float*)alloc(2 * Nc * 2 * 4);
  float* pbf  = (float*)alloc(Fc * 4);
  float* b1f  = (float*)alloc(Hc * 4);
  float* b2f  = (float*)alloc(Fc * 4);
  u16* Wbup = (u16*)alloc((size_t)Fc * 256 * 2);
  u16* Wyp  = (u16*)alloc((size_t)128 * Fc * 8 * 2);   // [1024/8][512][8] bf16, 1 MB
  u16* W1p  = (u16*)alloc((size_t)Fc * Hc * 2);
  u16* W2p  = (u16*)alloc((size_t)Hc * Fc * 2);
  u16* pwp  = (u16*)alloc((size_t)1024 * Fc * 2);
  u16* Cpm  = (u16*)alloc((size_t)256 * Fc * 2);
  size_t off_static = off;

  const size_t U = (size_t)Sc * Fc * 2;   // 8.39 MB per batch unit
  int nb = 4;
  while (nb > 1 && off_static + (size_t)nb * 4 * U + 4096 > ws_size) nb >>= 1;

  // hxl: [rows][1024] bf16 = [xh(256)|xl(256)|h(512)]  (2*nb*U)
  u16*   hxl  = (u16*)  alloc((size_t)nb * U * 2);
  float* Bu   = (float*)alloc((size_t)nb * U);
  u16*   out1 = (u16*)  alloc((size_t)nb * U);
  // MLP overlays: h2 -> Bu region (dead after xs_t); tbuf -> hxl region (dead
  // after gemm_y). tbuf holds (rows/2)*Hc*2 = 2*nb*U bytes = hxl size exactly.
  u16* tch = hxl;
  u16* h2  = (u16*)Bu;

  // detection + scalar conversions
  k_detect<<<1, 64, 0, stream>>>((const u16*)d_in[0], flag);
  k_convert<<<2, 256, 0, stream>>>(d_in[19], pbf, Fc, flag);
  k_convert<<<8, 256, 0, stream>>>(d_in[23], b1f, Hc, flag);
  k_convert<<<2, 256, 0, stream>>>(d_in[25], b2f, Fc, flag);
  // mods
  k_mods_init<<<12, 256, 0, stream>>>(d_in[21], flag, mods);
  k_mods2<<<dim3(12, Bc, 4), 256, 0, stream>>>(d_in[1], d_in[20], flag, mods);
  // S5 weights
  k_prep<<<dim3(2, 8), 64, 0, stream>>>(d_in[2], d_in[3], d_in[4], d_in[5], d_in[9],
                                        d_in[10], d_in[11], d_in[12], d_in[13], d_in[17],
                                        flag, Wbup, Abar);
  k_P2p<<<(Fc * Fc) / 256, 256, 0, stream>>>(d_in[8], d_in[16], d_in[18], flag, Wyp);
  // G via MFMA -> Wyp rows 0..511 (dup)
  k_Wpack<<<256, 256, 0, stream>>>(d_in[18], flag, 9, pwp);
  k_Cpm<<<256, 256, 0, stream>>>(d_in[6], d_in[7], d_in[14], d_in[15], flag, Cpm);
  k_Gp2<<<dim3(4, 2), 256, 0, stream>>>(Cpm, pwp, Wyp);
  // MLP weights
  k_Wpack<<<512, 256, 0, stream>>>(d_in[22], flag, 11, W1p);
  k_Wpack<<<512, 256, 0, stream>>>(d_in[24], flag, 9, W2p);

  for (int b0 = 0; b0 < Bc; b0 += nb) {
    long tok_base = (long)b0 * Sc;
    long rows = (long)nb * Sc;
    k_ln<<<rows, 256, 0, stream>>>(d_in[0], 0, tok_base, b0, flag, mods, 0, Fc, hxl, 1024, 512);
    k_gemm_bu<<<dim3(2, rows / 128), 256, 0, stream>>>(hxl + 512, Wbup, nb, Bu);
    k_scan<<<2 * nb * 64, 256, 0, stream>>>(Bu, Abar, nb);
    k_xs_t<<<rows / 32, 256, 0, stream>>>(Bu, nb, hxl);
    k_gemm_y<<<dim3(2, rows / 256), 512, 0, stream>>>(hxl, Wyp, d_in[0], tok_base, b0,
                                                      flag, mods, pbf, out1);
    k_ln<<<rows, 256, 0, stream>>>(out1, 1, 0, b0, flag, mods, 3 * Fc, 4 * Fc, h2, 512, 0);
    long RC = rows / 2;
    for (int ch = 0; ch < 2; ++ch) {
      long crow0 = ch * RC;
      k_mlp1<<<dim3(8, RC / 256), 512, 0, stream>>>(h2, W1p, b1f, crow0, tch);
      k_mlp2<<<dim3(4, RC / 128), 256, 0, stream>>>(tch, W2p, b2f, out1, mods, crow0,
                                                    tok_base, b0, flag, d_out);
    }
  }
  (void)n_in; (void)out_size; (void)in_sizes;
}

// Round 6
// 621.570 us; speedup vs baseline: 1.3420x; 1.0031x over previous
//
#include <hip/hip_runtime.h>
#include <hip/hip_bf16.h>

typedef unsigned short u16;
typedef __attribute__((ext_vector_type(8))) short bf16x8;
typedef __attribute__((ext_vector_type(4))) float f32x4;

#define Bc 4
#define Sc 8192
#define Fc 512
#define Nc 64
#define Hc 2048
#define SIXF 3072

__device__ __forceinline__ u16 f2bf(float v) {
  __hip_bfloat16 h = __float2bfloat16(v);
  return *reinterpret_cast<u16*>(&h);
}
__device__ __forceinline__ float bf2f(u16 u) {
  return __uint_as_float(((unsigned)u) << 16);
}
__device__ __forceinline__ float ldf(const void* p, long i, int bf) {
  return bf ? bf2f(((const u16*)p)[i]) : ((const float*)p)[i];
}

// async global->LDS, 16 bytes per lane. LDS dest is wave-uniform base + lane*16.
__device__ __forceinline__ void ld16(const u16* g, u16* l) {
  __builtin_amdgcn_global_load_lds(
      (const __attribute__((address_space(1))) unsigned int*)g,
      (__attribute__((address_space(3))) unsigned int*)l,
      16, 0, 0);
}

// XCD-aware bijective block remap (valid when nwg % 8 == 0; identity otherwise).
__device__ __forceinline__ void xcd_swz(int& bx, int& by) {
  int gx = gridDim.x;
  int nwg = gx * gridDim.y;
  int lin = blockIdx.x + gx * blockIdx.y;
  if ((nwg & 7) == 0) {
    int q = nwg >> 3;
    lin = (lin & 7) * q + (lin >> 3);
  }
  bx = lin % gx;
  by = lin / gx;
}

// ---------- dtype detection ----------
__global__ void k_detect(const u16* __restrict__ x, int* __restrict__ flag) {
  if (threadIdx.x == 0) {
    int cnt = 0;
    for (int i = 0; i < 256; ++i) {
      int e = (x[i] >> 7) & 0xFF;
      cnt += (e >= 130);
    }
    *flag = (cnt >= 16) ? 0 : 1;   // 1 = bf16 inputs, 0 = fp32
  }
}

__global__ void k_convert(const void* __restrict__ src, float* __restrict__ dst,
                          int n, const int* __restrict__ flag) {
  int bf = *flag;
  int i = blockIdx.x * blockDim.x + threadIdx.x;
  int stride = gridDim.x * blockDim.x;
  for (int j = i; j < n; j += stride) dst[j] = ldf(src, j, bf);
}

// ---------- mods ----------
__global__ __launch_bounds__(256) void k_mods_init(const void* __restrict__ ada_b,
                                                   const int* __restrict__ flag,
                                                   float* __restrict__ mods) {
  int bf = *flag;
  int col = blockIdx.x * 256 + threadIdx.x;   // grid 12
  float v = ldf(ada_b, col, bf);
  for (int b = 0; b < Bc; ++b) mods[b * SIXF + col] = v;
}

__global__ __launch_bounds__(256) void k_mods2(const void* __restrict__ cond,
                                               const void* __restrict__ ada_w,
                                               const int* __restrict__ flag,
                                               float* __restrict__ mods) {
  int bf = *flag;
  int b = blockIdx.y;
  int f0 = blockIdx.z * 128;
  int col = blockIdx.x * 256 + threadIdx.x;
  __shared__ float sc[128];
  for (int i = threadIdx.x; i < 128; i += 256) {
    float c = ldf(cond, b * Fc + f0 + i, bf);
    sc[i] = c / (1.f + expf(-c));
  }
  __syncthreads();
  float acc = 0.f;
  for (int f = 0; f < 128; ++f) acc = fmaf(sc[f], ldf(ada_w, (long)(f0 + f) * SIXF + col, bf), acc);
  atomicAdd(&mods[b * SIXF + col], acc);
}

// ---------- Abar + Wbu packed ----------
__global__ void k_prep(const void* lAf, const void* Aif, const void* Brf, const void* Bif, const void* ldtf,
                       const void* lAb, const void* Aib, const void* Brb, const void* Bib, const void* ldtb,
                       const int* __restrict__ flag,
                       u16* __restrict__ Wbup, float* __restrict__ Abar) {
  int bf = *flag;
  int dir = blockIdx.x;
  int f0 = blockIdx.y * 64;     // grid (2, 8)
  int n = threadIdx.x;          // 64
  const void* lA = dir ? lAb : lAf;
  const void* Ai = dir ? Aib : Aif;
  const void* Br = dir ? Brb : Brf;
  const void* Bi = dir ? Bib : Bif;
  const void* ld = dir ? ldtb : ldtf;
  float dt  = expf(ldf(ld, n, bf));
  float Are = -expf(ldf(lA, n, bf));
  float Aim = ldf(Ai, n, bf);
  float er  = expf(Are * dt);
  float abr = er * cosf(Aim * dt);
  float abi = er * sinf(Aim * dt);
  if (blockIdx.y == 0) {
    Abar[(dir * Nc + n) * 2 + 0] = abr;
    Abar[(dir * Nc + n) * 2 + 1] = abi;
  }
  float dr = Are + 1e-8f, di = Aim;
  float den = dr * dr + di * di;
  float nr = abr - 1.f, ni = abi;
  float cr = (nr * dr + ni * di) / den;
  float ci = (ni * dr - nr * di) / den;
  int col_re = dir * 128 + n, col_im = dir * 128 + 64 + n;
  for (int f = f0; f < f0 + 64; ++f) {
    float br = ldf(Br, n * Fc + f, bf), bi = ldf(Bi, n * Fc + f, bf);
    Wbup[(((f >> 3) * 256) + col_re) * 8 + (f & 7)] = f2bf(cr * br - ci * bi);
    Wbup[(((f >> 3) * 256) + col_im) * 8 + (f & 7)] = f2bf(cr * bi + ci * br);
  }
}

// P2 -> Wyp rows 512..1023 (packed [K/8][512][8], K=1024)
__global__ __launch_bounds__(256) void k_P2p(const void* Df, const void* Db, const void* pw,
                                             const int* __restrict__ flag, u16* __restrict__ Wyp) {
  int bf = *flag;
  int idx = blockIdx.x * 256 + threadIdx.x;
  int f1 = idx >> 9, fo = idx & 511;
  float v = ldf(Df, f1, bf) * ldf(pw, (long)f1 * Fc + fo, bf) +
            ldf(Db, f1, bf) * ldf(pw, (long)(Fc + f1) * Fc + fo, bf);
  Wyp[((((f1 >> 3) + 64) * Fc) + fo) * 8 + (f1 & 7)] = f2bf(v);
}

// Cpm bf16 [256][512]
__global__ __launch_bounds__(256) void k_Cpm(const void* Cref, const void* Cimf,
                                             const void* Creb, const void* Cimb,
                                             const int* __restrict__ flag, u16* __restrict__ Cpm) {
  int bf = *flag;
  int k = blockIdx.x;
  int dir = k >> 7, c = (k >> 6) & 1, n = k & 63;
  const void* C = dir ? (c ? Cimb : Creb) : (c ? Cimf : Cref);
  float sgn = c ? -1.f : 1.f;
  for (int f = threadIdx.x; f < Fc; f += 256)
    Cpm[k * Fc + f] = f2bf(sgn * ldf(C, (long)f * Nc + n, bf));
}

// generic raw [K,N] -> packed bf16 [K/8][N][8]
__global__ __launch_bounds__(256) void k_Wpack(const void* __restrict__ src, const int* __restrict__ flag,
                                               int log2N, u16* __restrict__ dst) {
  int bf = *flag;
  long i = (long)blockIdx.x * 256 + threadIdx.x;
  int Nn = 1 << log2N;
  long k8 = i >> log2N;
  int n = (int)(i & (Nn - 1));
  u16 tmp[8];
#pragma unroll
  for (int j = 0; j < 8; ++j)
    tmp[j] = f2bf(ldf(src, ((k8 << 3) + j) * (long)Nn + n, bf));
  *(ushort4*)(dst + i * 8)     = *(ushort4*)tmp;
  *(ushort4*)(dst + i * 8 + 4) = *(ushort4*)(tmp + 4);
}

// ---------- LayerNorm + AdaLN (dest stride/offset params for hxl fusion) ----------
__global__ __launch_bounds__(256) void k_ln(const void* __restrict__ src, int srcmode,
                                            long src_tok_base, int b0,
                                            const int* __restrict__ flag,
                                            const float* __restrict__ mods,
                                            int sh_base, int sc_base,
                                            u16* __restrict__ dst, int ldd, int dcol) {
  int bf = srcmode ? 1 : *flag;
  long lt = blockIdx.x;
  int b = b0 + (int)(lt >> 13);
  int t = threadIdx.x;
  long si = (src_tok_base + lt) * Fc;
  float x0 = ldf(src, si + t, bf);
  float x1 = ldf(src, si + t + 256, bf);
  float s = x0 + x1, qq = x0 * x0 + x1 * x1;
  for (int o = 32; o; o >>= 1) { s += __shfl_down(s, o); qq += __shfl_down(qq, o); }
  __shared__ float ss[4], sq[4];
  int w = t >> 6;
  if ((t & 63) == 0) { ss[w] = s; sq[w] = qq; }
  __syncthreads();
  float S = ss[0] + ss[1] + ss[2] + ss[3];
  float Q = sq[0] + sq[1] + sq[2] + sq[3];
  float mu = S * (1.f / Fc);
  float var = Q * (1.f / Fc) - mu * mu;
  float rs = rsqrtf(var + 1e-5f);
  const float* mb = mods + b * SIXF;
  float h0 = (x0 - mu) * rs * (1.f + mb[sc_base + t]) + mb[sh_base + t];
  float h1 = (x1 - mu) * rs * (1.f + mb[sc_base + t + 256]) + mb[sh_base + t + 256];
  dst[lt * (long)ldd + dcol + t] = f2bf(h0);
  dst[lt * (long)ldd + dcol + t + 256] = f2bf(h1);
}

// ---------- 128x128 MFMA core (256 thr): 2-barrier counted-vmcnt pipeline ----------
struct SmemA { u16 As[2][128 * 64]; u16 Ws[2][64 * 128]; };   // 64 KB

__device__ __forceinline__ void mfma_gemm128(SmemA& sm, const u16* __restrict__ A, long row0,
                                             int lda, int K,
                                             const u16* __restrict__ Wp, int N, int col0,
                                             f32x4 (&acc)[4][4]) {
  const int tid = threadIdx.x;
  const int l = tid & 63, q = l >> 4, li = l & 15;
  const int w = tid >> 6;
  const int wm = (w >> 1) << 6, wn = (w & 1) << 6;
  const int m0 = tid >> 3;                          // 0..31
  const int kc0 = (tid & 7) ^ (m0 & 7);             // invariant under m0+32
  const long aoff0 = (row0 + m0) * (long)lda + (kc0 << 3);
  const long woff0 = (long)(tid >> 7) * ((long)N << 3) + ((long)(col0 + (tid & 127)) << 3);
  const int lb = w << 9;
  const int T = K >> 6;
  int cur = 0;
  auto stage = [&](int buf, int k0) {
#pragma unroll
    for (int it = 0; it < 4; ++it)
      ld16(A + aoff0 + (long)it * ((long)lda << 5) + k0, sm.As[buf] + (it << 11) + lb);
#pragma unroll
    for (int it = 0; it < 4; ++it)
      ld16(Wp + woff0 + (long)k0 * N + (long)it * ((long)N << 4), sm.Ws[buf] + (it << 11) + lb);
  };
  stage(0, 0);
  for (int t = 0; t < T; ++t) {
    if (t + 1 < T) {
      stage(cur ^ 1, (t + 1) << 6);
      asm volatile("s_waitcnt vmcnt(8)" ::: "memory");
    } else {
      asm volatile("s_waitcnt vmcnt(0)" ::: "memory");
    }
    __builtin_amdgcn_s_barrier();
    __builtin_amdgcn_sched_barrier(0);
    const u16* As = sm.As[cur];
    const u16* Ws = sm.Ws[cur];
#pragma unroll
    for (int ks = 0; ks < 2; ++ks) {
      bf16x8 af[4], bw[4];
#pragma unroll
      for (int mt = 0; mt < 4; ++mt) {
        int mrow = wm + (mt << 4) + li;
        af[mt] = *(const bf16x8*)(As + (((mrow << 3) + (((ks << 2) + q) ^ (mrow & 7))) << 3));
      }
#pragma unroll
      for (int nt = 0; nt < 4; ++nt) {
        int n = wn + (nt << 4) + li;
        bw[nt] = *(const bf16x8*)(Ws + (((((ks << 2) + q) << 7) | n) << 3));
      }
#pragma unroll
      for (int mt = 0; mt < 4; ++mt)
#pragma unroll
        for (int nt = 0; nt < 4; ++nt)
          acc[mt][nt] = __builtin_amdgcn_mfma_f32_16x16x32_bf16(af[mt], bw[nt], acc[mt][nt], 0, 0, 0);
    }
    __builtin_amdgcn_s_barrier();
    __builtin_amdgcn_sched_barrier(0);
    cur ^= 1;
  }
}

// ---------- 256x256 MFMA core, depth-3 pipeline (512 thr, 8 waves 2x4) ----------
// BK=32, 4-slot LDS ring (128 KB). Each iter issues stage(t+3); vmcnt(12) keeps
// 3 stages (12 loads) in flight across 3 iterations -> ~3 MFMA-phases of
// latency/BW cover. A stored with chunk swizzle kc' = kc ^ ((m>>1)&3):
// stage source pre-swizzle (tid&3)^((tid>>3)&3) (round-invariant), read at
// q ^ ((mrow>>1)&3) -> 16 lanes span all 8 bank-slot classes twice (2-way, free).
// Ring WAR: slot (t+3)&3 = (t-1)&3 rewritten at iter t; its readers (tile t-1)
// finished at iter t-1's post-MFMA barrier.
struct SmemC { u16 As[4][256 * 32]; u16 Ws[4][32 * 256]; };   // 128 KB

__device__ __forceinline__ void mfma_gemm256(SmemC& sm, const u16* __restrict__ A, long row0,
                                             int lda, int K,
                                             const u16* __restrict__ Wp, int N, int col0,
                                             f32x4 (&acc)[8][4]) {
  const int tid = threadIdx.x;
  const int l = tid & 63, q = l >> 4, li = l & 15;
  const int w = tid >> 6;
  const int wm = (w >> 2) << 7, wn = (w & 3) << 6;
  const int m0 = tid >> 2;                          // 0..127
  const int kc0 = (tid & 3) ^ ((tid >> 3) & 3);     // round-invariant pre-swizzle
  const long aoff0 = (row0 + m0) * (long)lda + (kc0 << 3);
  const long woff0 = (long)(tid >> 8) * ((long)N << 3) + ((long)(col0 + (tid & 255)) << 3);
  const int T = K >> 5;
  auto stage = [&](int buf, int t) {
    const int k0 = t << 5;
#pragma unroll
    for (int it = 0; it < 2; ++it)
      ld16(A + aoff0 + (long)(it << 7) * lda + k0, sm.As[buf] + (((it << 9) + tid) << 3));
#pragma unroll
    for (int it = 0; it < 2; ++it)
      ld16(Wp + woff0 + (((long)((k0 >> 3) + (it << 1)) * N) << 3),
           sm.Ws[buf] + (((it << 9) + tid) << 3));
  };
  stage(0, 0); stage(1, 1); stage(2, 2);            // prologue: 3 stages in flight
  for (int t = 0; t < T; ++t) {
    if (t + 3 < T) stage((t + 3) & 3, t + 3);
    int rem = T - 1 - t;                            // stages newer than t
    if (rem >= 3)      asm volatile("s_waitcnt vmcnt(12)" ::: "memory");
    else if (rem == 2) asm volatile("s_waitcnt vmcnt(8)" ::: "memory");
    else if (rem == 1) asm volatile("s_waitcnt vmcnt(4)" ::: "memory");
    else               asm volatile("s_waitcnt vmcnt(0)" ::: "memory");
    __builtin_amdgcn_s_barrier();
    __builtin_amdgcn_sched_barrier(0);
    const u16* As = sm.As[t & 3];
    const u16* Ws = sm.Ws[t & 3];
    __builtin_amdgcn_s_setprio(1);
    bf16x8 bw[4];
#pragma unroll
    for (int nt = 0; nt < 4; ++nt) {
      int n = wn + (nt << 4) + li;
      bw[nt] = *(const bf16x8*)(Ws + (((q << 8) | n) << 3));
    }
#pragma unroll
    for (int mt = 0; mt < 8; ++mt) {
      int mrow = wm + (mt << 4) + li;
      bf16x8 af = *(const bf16x8*)(As + (((mrow << 2) + (q ^ ((mrow >> 1) & 3))) << 3));
#pragma unroll
      for (int nt = 0; nt < 4; ++nt)
        acc[mt][nt] = __builtin_amdgcn_mfma_f32_16x16x32_bf16(af, bw[nt], acc[mt][nt], 0, 0, 0);
    }
    __builtin_amdgcn_s_setprio(0);
    __builtin_amdgcn_s_barrier();
    __builtin_amdgcn_sched_barrier(0);
  }
}

// G via MFMA: Cpm[256,512] @ pwp(dir half) -> Wyp rows 0..255 AND dup rows 256..511
__global__ __launch_bounds__(256) void k_Gp2(const u16* __restrict__ Cpm, const u16* __restrict__ pwp,
                                             u16* __restrict__ Wyp) {
  __shared__ SmemA sm;
  f32x4 acc[4][4] = {};
  int bx, by; xcd_swz(bx, by);
  long row0 = (long)by * 128;
  int col0 = bx << 7;
  int dir = (int)(row0 >> 7);
  mfma_gemm128(sm, Cpm, row0, Fc, Fc, pwp + (size_t)dir * 262144, Fc, col0, acc);
  const int l = threadIdx.x & 63, q = l >> 4, li = l & 15;
  const int w = threadIdx.x >> 6;
  const int wm = (w >> 1) << 6, wn = (w & 1) << 6;
#pragma unroll
  for (int mt = 0; mt < 4; ++mt)
#pragma unroll
    for (int nt = 0; nt < 4; ++nt)
#pragma unroll
      for (int r = 0; r < 4; ++r) {
        int k = (int)row0 + wm + (mt << 4) + (q << 2) + r;
        int col = col0 + wn + (nt << 4) + li;
        u16 v = f2bf(acc[mt][nt][r]);
        size_t i0 = (((size_t)(k >> 3)) * Fc + col) * 8 + (k & 7);
        Wyp[i0] = v;
        Wyp[i0 + (size_t)32 * Fc * 8] = v;   // duplicate for xl half
      }
}

// Bu GEMM: h (hxl cols 512..1023) @ Wbu -> Bu[dir][lb][n][s][2]
__global__ __launch_bounds__(256) void k_gemm_bu(const u16* __restrict__ hp,
                                                 const u16* __restrict__ Wbup,
                                                 int nb, float* __restrict__ Bu) {
  __shared__ SmemA sm;
  f32x4 acc[4][4] = {};
  int bx, by; xcd_swz(bx, by);
  long row0 = (long)by * 128;
  int col0 = bx << 7;
  mfma_gemm128(sm, hp, row0, 1024, Fc, Wbup, 256, col0, acc);
  const int l = threadIdx.x & 63, q = l >> 4, li = l & 15;
  const int w = threadIdx.x >> 6;
  const int wm = (w >> 1) << 6, wn = (w & 1) << 6;
#pragma unroll
  for (int mt = 0; mt < 4; ++mt) {
#pragma unroll
    for (int nt = 0; nt < 4; ++nt) {
      int col = col0 + wn + (nt << 4) + li;
      int dir = col >> 7, cc = (col >> 6) & 1, n = col & 63;
#pragma unroll
      for (int r = 0; r < 4; ++r) {
        long lt = row0 + wm + (mt << 4) + (q << 2) + r;
        int lb = (int)(lt >> 13), s = (int)(lt & 8191);
        int spos = dir ? (Sc - 1 - s) : s;
        Bu[((((long)dir * nb + lb) * Nc + n) * Sc + spos) * 2 + cc] = acc[mt][nt][r];
      }
    }
  }
}

// chunked complex linear scan, in-place on Bu
__global__ __launch_bounds__(256) void k_scan(float* __restrict__ Bu, const float* __restrict__ Abar,
                                              int nb) {
  int blk = blockIdx.x;
  int per_dir = nb * 64;
  int dir = blk / per_dir;
  int rem = blk - dir * per_dir;
  int lb = rem >> 6, n = rem & 63;
  float ar = Abar[(dir * Nc + n) * 2 + 0];
  float ai = Abar[(dir * Nc + n) * 2 + 1];
  float* base = Bu + (((long)dir * nb + lb) * Nc + n) * Sc * 2;
  int t = threadIdx.x;
  float4 loc[16];
  float lr = 0.f, li = 0.f;
  const float4* bp = (const float4*)base + t * 16;
#pragma unroll
  for (int j = 0; j < 16; ++j) {
    float4 v = bp[j];
    loc[j] = v;
    float nr = fmaf(ar, lr, fmaf(-ai, li, v.x));
    float ni = fmaf(ar, li, fmaf(ai, lr, v.y));
    lr = fmaf(ar, nr, fmaf(-ai, ni, v.z));
    li = fmaf(ar, ni, fmaf(ai, nr, v.w));
  }
  __shared__ float sr[256], si[256];
  float pr = ar, pi = ai;
  for (int k = 0; k < 5; ++k) { float t2 = pr * pr - pi * pi; pi = 2.f * pr * pi; pr = t2; }  // a^32
  float vr = lr, vi = li;
  for (int step = 1; step < 256; step <<= 1) {
    sr[t] = vr; si[t] = vi;
    __syncthreads();
    if (t >= step) {
      float orr = sr[t - step], oii = si[t - step];
      vr = vr + pr * orr - pi * oii;
      vi = vi + pr * oii + pi * orr;
    }
    __syncthreads();
    float t2 = pr * pr - pi * pi; pi = 2.f * pr * pi; pr = t2;
  }
  sr[t] = vr; si[t] = vi;
  __syncthreads();
  float xr = (t == 0) ? 0.f : sr[t - 1];
  float xi = (t == 0) ? 0.f : si[t - 1];
  float4* op = (float4*)base + t * 16;
#pragma unroll
  for (int j = 0; j < 16; ++j) {
    float4 v = loc[j];
    float nr = fmaf(ar, xr, fmaf(-ai, xi, v.x));
    float ni = fmaf(ar, xi, fmaf(ai, xr, v.y));
    xr = fmaf(ar, nr, fmaf(-ai, ni, v.z));
    xi = fmaf(ar, ni, fmaf(ai, nr, v.w));
    float4 o; o.x = nr; o.y = ni; o.z = xr; o.w = xi;
    op[j] = o;
  }
}

// gather xs -> token-major bf16 hi/lo into hxl cols [0..255]=hi, [256..511]=lo
__global__ __launch_bounds__(256) void k_xs_t(const float* __restrict__ xs, int nb,
                                              u16* __restrict__ hxl) {
  __shared__ float tile[32 * 257];
  long t0 = (long)blockIdx.x * 32;
  int lb = (int)(t0 >> 13);
  int s0 = (int)(t0 & 8191);
  int tid = threadIdx.x;
  int ls = tid & 31;
  int half = (tid >> 5) & 1;
  int wv = tid >> 6;
#pragma unroll 4
  for (int cg = 0; cg < 32; ++cg) {
    int col = cg * 8 + wv * 2 + half;
    int dir = col >> 7, cc = (col >> 6) & 1, n = col & 63;
    int spos = dir ? (Sc - 1 - (s0 + ls)) : (s0 + ls);
    float v = xs[((((long)dir * nb + lb) * Nc + n) * Sc + spos) * 2 + cc];
    tile[ls * 257 + col] = v;
  }
  __syncthreads();
  for (int j = 0; j < 32; ++j) {
    float v = tile[j * 257 + tid];
    u16 hi = f2bf(v);
    long lt = t0 + j;
    hxl[lt * 1024 + tid] = hi;
    hxl[lt * 1024 + 256 + tid] = f2bf(v - bf2f(hi));
  }
}

// out1 = bf16( x + g1*([xh|xl|h] @ [Gp;Gp;P2p] + pb) )   -- single fused K=1024 pass
__global__ __launch_bounds__(512, 2) void k_gemm_y(const u16* __restrict__ hxl,
                                                   const u16* __restrict__ Wyp,
                                                   const void* __restrict__ xraw, long tok_base, int b0,
                                                   const int* __restrict__ flag,
                                                   const float* __restrict__ mods,
                                                   const float* __restrict__ pb,
                                                   u16* __restrict__ out1) {
  __shared__ SmemC sm;
  f32x4 acc[8][4] = {};
  int bx, by; xcd_swz(bx, by);
  long row0 = (long)by << 8;
  int col0 = bx << 8;
  mfma_gemm256(sm, hxl, row0, 1024, 1024, Wyp, Fc, col0, acc);
  int bf = *flag;
  const int l = threadIdx.x & 63, q = l >> 4, li = l & 15;
  const int w = threadIdx.x >> 6;
  const int wm = (w >> 2) << 7, wn = (w & 3) << 6;
#pragma unroll
  for (int mt = 0; mt < 8; ++mt) {
#pragma unroll
    for (int r = 0; r < 4; ++r) {
      long lt = row0 + wm + (mt << 4) + (q << 2) + r;
      int b = b0 + (int)(lt >> 13);
      const float* mb = mods + b * SIXF + 2 * Fc;
#pragma unroll
      for (int nt = 0; nt < 4; ++nt) {
        int col = col0 + wn + (nt << 4) + li;
        float xv = ldf(xraw, (tok_base + lt) * Fc + col, bf);
        out1[lt * Fc + col] = f2bf(xv + mb[col] * (acc[mt][nt][r] + pb[col]));
      }
    }
  }
}

// tanh-approx gelu via hardware exp2+rcp
__device__ __forceinline__ float gelu_t(float u) {
  float z = 0.7978845608028654f * fmaf(0.044715f * u * u, u, u);
  float e = __builtin_amdgcn_exp2f(z * -2.8853900817779268f);   // exp(-2z)
  return u * __builtin_amdgcn_rcpf(1.f + e);
}

__global__ __launch_bounds__(512, 2) void k_mlp1(const u16* __restrict__ h2, const u16* __restrict__ W1p,
                                                 const float* __restrict__ b1, long crow0,
                                                 u16* __restrict__ tbuf) {
  __shared__ SmemC sm;
  f32x4 acc[8][4] = {};
  int bx, by; xcd_swz(bx, by);
  long row0 = crow0 + ((long)by << 8);
  int col0 = bx << 8;
  mfma_gemm256(sm, h2, row0, Fc, Fc, W1p, Hc, col0, acc);
  const int l = threadIdx.x & 63, q = l >> 4, li = l & 15;
  const int w = threadIdx.x >> 6;
  const int wm = (w >> 2) << 7, wn = (w & 3) << 6;
#pragma unroll
  for (int mt = 0; mt < 8; ++mt) {
#pragma unroll
    for (int r = 0; r < 4; ++r) {
      long lr2 = row0 - crow0 + wm + (mt << 4) + (q << 2) + r;
#pragma unroll
      for (int nt = 0; nt < 4; ++nt) {
        int col = col0 + wn + (nt << 4) + li;
        tbuf[lr2 * Hc + col] = f2bf(gelu_t(acc[mt][nt][r] + b1[col]));
      }
    }
  }
}

__global__ __launch_bounds__(256) void k_mlp2(const u16* __restrict__ tbuf, const u16* __restrict__ W2p,
                                              const float* __restrict__ b2, const u16* __restrict__ out1,
                                              const float* __restrict__ mods, long crow0,
                                              long tok_base, int b0,
                                              const int* __restrict__ flag, void* __restrict__ dout) {
  __shared__ SmemA sm;
  f32x4 acc[4][4] = {};
  int bx, by; xcd_swz(bx, by);
  long lrow0 = (long)by * 128;
  int col0 = bx << 7;
  mfma_gemm128(sm, tbuf, lrow0, Hc, Hc, W2p, Fc, col0, acc);
  int bf = *flag;
  const int l = threadIdx.x & 63, q = l >> 4, li = l & 15;
  const int w = threadIdx.x >> 6;
  const int wm = (w >> 1) << 6, wn = (w & 1) << 6;
#pragma unroll
  for (int mt = 0; mt < 4; ++mt) {
#pragma unroll
    for (int r = 0; r < 4; ++r) {
      long lt = crow0 + lrow0 + wm + (mt << 4) + (q << 2) + r;
      int b = b0 + (int)(lt >> 13);
      const float* mb = mods + b * SIXF + 5 * Fc;
#pragma unroll
      for (int nt = 0; nt < 4; ++nt) {
        int col = col0 + wn + (nt << 4) + li;
        float v = bf2f(out1[lt * Fc + col]) + mb[col] * (acc[mt][nt][r] + b2[col]);
        long oi = (tok_base + lt) * Fc + col;
        if (bf) ((u16*)dout)[oi] = f2bf(v);
        else    ((float*)dout)[oi] = v;
      }
    }
  }
}

extern "C" void kernel_launch(void* const* d_in, const int* in_sizes, int n_in,
                              void* d_out, int out_size, void* d_ws, size_t ws_size,
                              hipStream_t stream) {
  char* ws = (char*)d_ws;
  size_t off = 0;
  auto alloc = [&](size_t bytes) -> char* {
    char* p = ws + off;
    off += (bytes + 255) & ~(size_t)255;
    return p;
  };
  int*   flag = (int*)  alloc(4);
  float* mods = (float*)alloc((size_t)Bc * SIXF * 4);
  float* Abar = (float*)alloc(2 * Nc * 2 * 4);
  float* pbf  = (float*)alloc(Fc * 4);
  float* b1f  = (float*)alloc(Hc * 4);
  float* b2f  = (float*)alloc(Fc * 4);
  u16* Wbup = (u16*)alloc((size_t)Fc * 256 * 2);
  u16* Wyp  = (u16*)alloc((size_t)128 * Fc * 8 * 2);   // [1024/8][512][8] bf16, 1 MB
  u16* W1p  = (u16*)alloc((size_t)Fc * Hc * 2);
  u16* W2p  = (u16*)alloc((size_t)Hc * Fc * 2);
  u16* pwp  = (u16*)alloc((size_t)1024 * Fc * 2);
  u16* Cpm  = (u16*)alloc((size_t)256 * Fc * 2);
  size_t off_static = off;

  const size_t U = (size_t)Sc * Fc * 2;   // 8.39 MB per batch unit
  int nb = 4;
  while (nb > 1 && off_static + (size_t)nb * 4 * U + 4096 > ws_size) nb >>= 1;

  // hxl: [rows][1024] bf16 = [xh(256)|xl(256)|h(512)]  (2*nb*U)
  u16*   hxl  = (u16*)  alloc((size_t)nb * U * 2);
  float* Bu   = (float*)alloc((size_t)nb * U);
  u16*   out1 = (u16*)  alloc((size_t)nb * U);
  // MLP overlays: h2 -> Bu region (dead after xs_t); tbuf -> hxl region (dead
  // after gemm_y). tbuf holds (rows/2)*Hc*2 = 2*nb*U bytes = hxl size exactly.
  u16* tch = hxl;
  u16* h2  = (u16*)Bu;

  // detection + scalar conversions
  k_detect<<<1, 64, 0, stream>>>((const u16*)d_in[0], flag);
  k_convert<<<2, 256, 0, stream>>>(d_in[19], pbf, Fc, flag);
  k_convert<<<8, 256, 0, stream>>>(d_in[23], b1f, Hc, flag);
  k_convert<<<2, 256, 0, stream>>>(d_in[25], b2f, Fc, flag);
  // mods
  k_mods_init<<<12, 256, 0, stream>>>(d_in[21], flag, mods);
  k_mods2<<<dim3(12, Bc, 4), 256, 0, stream>>>(d_in[1], d_in[20], flag, mods);
  // S5 weights
  k_prep<<<dim3(2, 8), 64, 0, stream>>>(d_in[2], d_in[3], d_in[4], d_in[5], d_in[9],
                                        d_in[10], d_in[11], d_in[12], d_in[13], d_in[17],
                                        flag, Wbup, Abar);
  k_P2p<<<(Fc * Fc) / 256, 256, 0, stream>>>(d_in[8], d_in[16], d_in[18], flag, Wyp);
  // G via MFMA -> Wyp rows 0..511 (dup)
  k_Wpack<<<256, 256, 0, stream>>>(d_in[18], flag, 9, pwp);
  k_Cpm<<<256, 256, 0, stream>>>(d_in[6], d_in[7], d_in[14], d_in[15], flag, Cpm);
  k_Gp2<<<dim3(4, 2), 256, 0, stream>>>(Cpm, pwp, Wyp);
  // MLP weights
  k_Wpack<<<512, 256, 0, stream>>>(d_in[22], flag, 11, W1p);
  k_Wpack<<<512, 256, 0, stream>>>(d_in[24], flag, 9, W2p);

  for (int b0 = 0; b0 < Bc; b0 += nb) {
    long tok_base = (long)b0 * Sc;
    long rows = (long)nb * Sc;
    k_ln<<<rows, 256, 0, stream>>>(d_in[0], 0, tok_base, b0, flag, mods, 0, Fc, hxl, 1024, 512);
    k_gemm_bu<<<dim3(2, rows / 128), 256, 0, stream>>>(hxl + 512, Wbup, nb, Bu);
    k_scan<<<2 * nb * 64, 256, 0, stream>>>(Bu, Abar, nb);
    k_xs_t<<<rows / 32, 256, 0, stream>>>(Bu, nb, hxl);
    k_gemm_y<<<dim3(2, rows / 256), 512, 0, stream>>>(hxl, Wyp, d_in[0], tok_base, b0,
                                                      flag, mods, pbf, out1);
    k_ln<<<rows, 256, 0, stream>>>(out1, 1, 0, b0, flag, mods, 3 * Fc, 4 * Fc, h2, 512, 0);
    long RC = rows / 2;
    for (int ch = 0; ch < 2; ++ch) {
      long crow0 = ch * RC;
      k_mlp1<<<dim3(8, RC / 256), 512, 0, stream>>>(h2, W1p, b1f, crow0, tch);
      k_mlp2<<<dim3(4, RC / 128), 256, 0, stream>>>(tch, W2p, b2f, out1, mods, crow0,
                                                    tok_base, b0, flag, d_out);
    }
  }
  (void)n_in; (void)out_size; (void)in_sizes;
}